// Round 3
// baseline (333.580 us; speedup 1.0000x reference)
//
#include <hip/hip_runtime.h>

// B=32, C=512, c2=256, M=1024. All GEMMs bf16 MFMA (fp32 accum), m97-style:
// 128x128 (or fused) tiles, BK=64, global_load_lds(16B) staging, XOR-swizzled
// chunks.
//
// P0 : x[b][c][sp] fp32 -> xT[b*1024+sp][c] bf16
// W0 : weight casts (Wkv = [Wk;Wv] 512x512, Wo 512x256)
// K1 : [32768x512]x[512x512]: k-half -> kT[m][c] + row-sum partials,
//      v-half -> vT[b][c][n] (reshape-permuted)
// K2 : FUSED flash-style attention per (64-row m-stripe, batch), v3:
//      A-stripe (chunk-invariant) held in REGISTERS (one-time LDS fill,
//      saves 32 ds_read_b128/wave/chunk), K1b row-sum combine folded into
//      prologue, wave-self-contained 4KB staging rounds, counted vmcnt(4),
//      2 raw s_barriers per chunk, setprio, bijective XCD swizzle.
// K3 : out = Wo @ O2 + bo + x (fp32), B = OB (k-major)

typedef short bf8 __attribute__((ext_vector_type(8)));
typedef float f32x4 __attribute__((ext_vector_type(4)));

#define MFMA16(a, b, c) __builtin_amdgcn_mfma_f32_16x16x32_bf16((a), (b), (c), 0, 0, 0)

__device__ __forceinline__ short f2bf(float x) {
  unsigned u = __float_as_uint(x);
  u += 0x7fffu + ((u >> 16) & 1u);   // RNE, finite inputs
  return (short)(u >> 16);
}

__device__ __forceinline__ void gll16(const short* g, void* l) {
  __builtin_amdgcn_global_load_lds(
      (const __attribute__((address_space(1))) unsigned int*)g,
      (__attribute__((address_space(3))) unsigned int*)l, 16, 0, 0);
}

__device__ __forceinline__ void lgkm0() {
  asm volatile("s_waitcnt lgkmcnt(0)" ::: "memory");
}
template <int N>
__device__ __forceinline__ void waitv() {
  static_assert(N == 0 || N == 4 || N == 8, "bad vmcnt");
  if constexpr (N == 0) asm volatile("s_waitcnt vmcnt(0)" ::: "memory");
  else if constexpr (N == 4) asm volatile("s_waitcnt vmcnt(4)" ::: "memory");
  else asm volatile("s_waitcnt vmcnt(8)" ::: "memory");
}
__device__ __forceinline__ void barrier_relaxed() {
  asm volatile("" ::: "memory");
  __builtin_amdgcn_s_barrier();
  asm volatile("" ::: "memory");
}

// ---- shared GEMM core v3: C[128][128] tile, A/B k-major bf16, K=ksteps*64.
// Double-buffered counted-vmcnt pipeline: smem = 2 x (16KB A | 16KB B).
__device__ __forceinline__ void gemm_core(const short* __restrict__ A,
                                          const short* __restrict__ B,
                                          int ldA, int ldB, int ksteps,
                                          char* smem, f32x4 acc[4][4]) {
  const int tid = threadIdx.x;
  const int w = tid >> 6, l = tid & 63;
  const int q = l >> 4, i = l & 15;
  const int wm = w & 1, wn = w >> 1;
  const int srow = l >> 3;
  const int gcol = ((l & 7) ^ srow) * 8;        // swizzled 16B chunk (shorts)
  f32x4 zz = {0.f, 0.f, 0.f, 0.f};
  #pragma unroll
  for (int mt = 0; mt < 4; ++mt)
    #pragma unroll
    for (int nt = 0; nt < 4; ++nt) acc[mt][nt] = zz;

  auto stage = [&](int ks, char* buf) {
    const short* Ak = A + ks * 64 + gcol;
    const short* Bk = B + ks * 64 + gcol;
    #pragma unroll
    for (int j = 0; j < 4; ++j) {
      int s = w * 4 + j;
      size_t row = (size_t)(s * 8 + srow);
      gll16(Ak + row * ldA, buf + s * 1024);
      gll16(Bk + row * ldB, buf + 16384 + s * 1024);
    }
  };

  stage(0, smem);
  for (int ks = 0; ks < ksteps; ++ks) {
    char* cur = smem + (ks & 1) * 32768;
    if (ks + 1 < ksteps) {
      stage(ks + 1, smem + ((ks + 1) & 1) * 32768);
      waitv<8>();                         // own stage(ks) done; ks+1 in flight
    } else {
      waitv<0>();
    }
    barrier_relaxed();                    // tile ks visible to all waves
    #pragma unroll
    for (int kq = 0; kq < 2; ++kq) {
      int sw = ((kq * 4 + q) ^ (i & 7)) * 16;   // swizzled read offset (bytes)
      bf8 af[4], bq[4];
      #pragma unroll
      for (int mt = 0; mt < 4; ++mt)
        af[mt] = *(const bf8*)(cur + (wm * 64 + mt * 16 + i) * 128 + sw);
      #pragma unroll
      for (int nt = 0; nt < 4; ++nt)
        bq[nt] = *(const bf8*)(cur + 16384 + (wn * 64 + nt * 16 + i) * 128 + sw);
      __builtin_amdgcn_s_setprio(1);
      #pragma unroll
      for (int mt = 0; mt < 4; ++mt)
        #pragma unroll
        for (int nt = 0; nt < 4; ++nt)
          acc[mt][nt] = MFMA16(af[mt], bq[nt], acc[mt][nt]);
      __builtin_amdgcn_s_setprio(0);
    }
    barrier_relaxed();                    // reads of cur done; safe to refill
  }
}

// ---------------- P0: transpose + convert x ----------------
__global__ __launch_bounds__(256) void p0_xpose(const float* __restrict__ x,
                                                short* __restrict__ xT) {
  __shared__ float lds[64][65];
  int cb = blockIdx.x, sb = blockIdx.y, b = blockIdx.z;
  int t = threadIdx.x;
  int c0 = cb * 64, sp0 = sb * 64;
  const float4* x4 = reinterpret_cast<const float4*>(x);
  #pragma unroll
  for (int j = 0; j < 4; ++j) {
    int lin = t + 256 * j;
    int cl = lin >> 4, s4 = lin & 15;
    float4 v = x4[(((size_t)b * 512 + c0 + cl) * 1024 + sp0 + s4 * 4) >> 2];
    lds[cl][s4 * 4 + 0] = v.x; lds[cl][s4 * 4 + 1] = v.y;
    lds[cl][s4 * 4 + 2] = v.z; lds[cl][s4 * 4 + 3] = v.w;
  }
  __syncthreads();
  int spl = t >> 2, cs = (t & 3) * 16;
  bf8 o0, o1;
  #pragma unroll
  for (int j = 0; j < 8; ++j) o0[j] = f2bf(lds[cs + j][spl]);
  #pragma unroll
  for (int j = 0; j < 8; ++j) o1[j] = f2bf(lds[cs + 8 + j][spl]);
  size_t base = ((size_t)b * 1024 + sp0 + spl) * 512 + c0 + cs;
  *reinterpret_cast<bf8*>(xT + base) = o0;
  *reinterpret_cast<bf8*>(xT + base + 8) = o1;
}

// ---------------- W0: weight casts ----------------
__global__ __launch_bounds__(256) void w0_weights(const float* __restrict__ Wk,
                                                  const float* __restrict__ Wv,
                                                  const float* __restrict__ Wo,
                                                  short* __restrict__ Wkv_bf,
                                                  short* __restrict__ Wo_bf) {
  int g = blockIdx.x * 256 + threadIdx.x;
  if (g < 262144) {
    int o = g >> 9, c = g & 511;
    float v = (o < 256) ? Wk[o * 512 + c] : Wv[(o - 256) * 512 + c];
    Wkv_bf[g] = f2bf(v);
  } else {
    int i2 = g - 262144;
    Wo_bf[i2] = f2bf(Wo[i2]);
  }
}

// ---------------- K1: fused k/v projection GEMM ----------------
__global__ __launch_bounds__(256, 2) void k1_kv(const short* __restrict__ xT,
                                                const short* __restrict__ Wkv,
                                                const float* __restrict__ bk,
                                                const float* __restrict__ bv,
                                                short* __restrict__ kT,
                                                short* __restrict__ vT,
                                                float* __restrict__ s_part) {
  __shared__ __attribute__((aligned(16))) char smem[65536];
  f32x4 acc[4][4];
  int bm = blockIdx.x, bn = blockIdx.y;
  gemm_core(xT + (size_t)bm * 128 * 512, Wkv + (size_t)bn * 128 * 512,
            512, 512, 8, smem, acc);
  int tid = threadIdx.x;
  int w = tid >> 6, l = tid & 63, q = l >> 4, i = l & 15;
  int wm = w & 1, wn = w >> 1;
  int mbase = bm * 128 + wm * 64;
  int nbase = bn * 128 + wn * 64;
  if (bn < 2) {                                  // k half
    float rp[4][4];
    #pragma unroll
    for (int mt = 0; mt < 4; ++mt)
      #pragma unroll
      for (int r = 0; r < 4; ++r) rp[mt][r] = 0.f;
    #pragma unroll
    for (int mt = 0; mt < 4; ++mt)
      #pragma unroll
      for (int nt = 0; nt < 4; ++nt) {
        float bias = bk[nbase + nt * 16 + i];
        #pragma unroll
        for (int r = 0; r < 4; ++r) {
          float val = acc[mt][nt][r] + bias;
          int mg = mbase + mt * 16 + q * 4 + r;
          kT[(size_t)mg * 256 + nbase + nt * 16 + i] = f2bf(val);
          rp[mt][r] += val;
        }
      }
    #pragma unroll
    for (int mask = 1; mask <= 8; mask <<= 1)
      #pragma unroll
      for (int mt = 0; mt < 4; ++mt)
        #pragma unroll
        for (int r = 0; r < 4; ++r) rp[mt][r] += __shfl_xor(rp[mt][r], mask, 64);
    if (i == 0) {
      int pg = bn * 2 + wn;
      #pragma unroll
      for (int mt = 0; mt < 4; ++mt)
        #pragma unroll
        for (int r = 0; r < 4; ++r)
          s_part[pg * 32768 + mbase + mt * 16 + q * 4 + r] = rp[mt][r];
    }
  } else {                                       // v half -> vT permuted
    #pragma unroll
    for (int mt = 0; mt < 4; ++mt)
      #pragma unroll
      for (int nt = 0; nt < 4; ++nt) {
        int o2 = nbase + nt * 16 + i - 256;
        float bias = bv[o2];
        #pragma unroll
        for (int r = 0; r < 4; ++r) {
          float val = acc[mt][nt][r] + bias;
          int mg = mbase + mt * 16 + q * 4 + r;
          int b = mg >> 10, sp = mg & 1023;
          vT[((size_t)b * 256 + (sp & 255)) * 1024 + 4 * o2 + (sp >> 8)] = f2bf(val);
        }
      }
  }
}

// ---------------- K2 v3: fused gram -> softmax -> PV -> OB ----------------
// Block = (64-row m-stripe bm, batch b), XCD-swizzled so each XCD owns 4
// batches. LDS: Apan 32K (prologue-only A reg-fill) | Ppan 16K | Bst 32K =
// 2 bufs x 4 waves x 4KB. A-stripe held in 128 VGPRs (af_r[4][2][4]) for
// all 8 chunks. Row-sum combine (ex-K1b) folded into prologue. Counted
// vmcnt(4), 2 raw s_barriers per chunk, setprio. 2 blocks/CU.
__global__ __launch_bounds__(256, 2) void k2_fused(const short* __restrict__ kT,
                                                   const short* __restrict__ vT,
                                                   const float* __restrict__ s_part,
                                                   short* __restrict__ OB) {
  __shared__ __attribute__((aligned(16))) char smem[81920];
  char* Apan = smem;            // 32 KB: prologue A staging (dead after fill)
  char* Ppan = smem + 32768;    // 16 KB: 2 panels x (64 rows x 128 B)
  char* Bst  = smem + 49152;    // 32 KB: 2 bufs x 4 waves x 4 KB

  const int id = blockIdx.x;
  const int xcd = id & 7, slot = id >> 3;
  const int b  = xcd * 4 + (slot >> 4);   // 4 batches per XCD (L2-resident)
  const int bm = slot & 15;

  const int tid = threadIdx.x;
  const int w = tid >> 6, l = tid & 63;
  const int q = l >> 4, i = l & 15;
  const int srow = l >> 3;
  const int gcol = ((l & 7) ^ srow) * 8;

  const short* kTb = kT + (size_t)b * 1024 * 256;
  const short* vTb = vT + (size_t)b * 256 * 1024;

  char* slabA = Bst + w * 4096;            // even rounds
  char* slabB = Bst + 16384 + w * 4096;    // odd rounds

  const float sc1 = 1.0f / 16384.0f;             // (1/M)/16
  const float sc2 = 1.0f / 16777216.0f;          // (1/M^2)/16

  // ---- issue resident-A staging FIRST (latency hidden under s-sums) ----
  {
    const short* Am = kTb + (size_t)bm * 64 * 256;
    #pragma unroll
    for (int ks = 0; ks < 4; ++ks)
      #pragma unroll
      for (int j2 = 0; j2 < 2; ++j2) {
        int s2 = w * 2 + j2;
        gll16(Am + (size_t)(s2 * 8 + srow) * 256 + ks * 64 + gcol,
              Apan + ks * 8192 + s2 * 1024);
      }
  }

  // ---- row-sum combine (ex-K1b) + scalar prefetch; completes pre-pipeline ----
  const int mglob = b * 1024;
  float sm2[4][4];
  #pragma unroll
  for (int mt = 0; mt < 4; ++mt)
    #pragma unroll
    for (int r = 0; r < 4; ++r) {
      int m = mglob + bm * 64 + mt * 16 + q * 4 + r;
      sm2[mt][r] = (s_part[m] + s_part[32768 + m] + s_part[65536 + m] +
                    s_part[98304 + m]) * sc2;
    }
  float sn[8][2];
  #pragma unroll
  for (int c = 0; c < 8; ++c)
    #pragma unroll
    for (int nt = 0; nt < 2; ++nt) {
      int m = mglob + c * 128 + w * 32 + nt * 16 + i;
      sn[c][nt] = s_part[m] + s_part[32768 + m] + s_part[65536 + m] +
                  s_part[98304 + m];
    }

  waitv<0>();                              // A (and s loads) landed
  barrier_relaxed();                       // A visible to all waves

  // ---- one-time A reg-fill: af_r[ks][kq][mt], 32 ds_read_b128 ----
  bf8 af_r[4][2][4];
  #pragma unroll
  for (int ks = 0; ks < 4; ++ks)
    #pragma unroll
    for (int kq = 0; kq < 2; ++kq) {
      int sw = ((kq * 4 + q) ^ (i & 7)) * 16;
      #pragma unroll
      for (int mt = 0; mt < 4; ++mt)
        af_r[ks][kq][mt] =
            *(const bf8*)(Apan + ks * 8192 + (mt * 16 + i) * 128 + sw);
    }

  // staging helpers: each wave stages exactly the rows its MFMAs read
  auto stageS = [&](int c, int ks, char* sl) {
    const short* Bn = kTb + (size_t)c * 128 * 256 + ks * 64 + gcol;
    #pragma unroll
    for (int j = 0; j < 4; ++j)
      gll16(Bn + (size_t)(w * 32 + j * 8 + srow) * 256, sl + j * 1024);
  };
  auto stageV = [&](int c, int ks2, int h, char* sl) {
    const short* Vn = vTb + c * 128 + ks2 * 64 + gcol;
    #pragma unroll
    for (int j = 0; j < 4; ++j)
      gll16(Vn + (size_t)(w * 64 + h * 32 + j * 8 + srow) * 1024, sl + j * 1024);
  };

  stageS(0, 0, slabA);                     // round 0
  stageS(0, 1, slabB);                     // round 1

  f32x4 zz = {0.f, 0.f, 0.f, 0.f};
  f32x4 acc_o[4][4];
  float rowsum[4][4];
  #pragma unroll
  for (int mt = 0; mt < 4; ++mt)
    #pragma unroll
    for (int ct = 0; ct < 4; ++ct) acc_o[mt][ct] = zz;
  #pragma unroll
  for (int mt = 0; mt < 4; ++mt)
    #pragma unroll
    for (int r = 0; r < 4; ++r) rowsum[mt][r] = 0.f;

  #pragma unroll
  for (int c = 0; c < 8; ++c) {
    f32x4 acc_s[4][2];
    #pragma unroll
    for (int mt = 0; mt < 4; ++mt)
      #pragma unroll
      for (int nt = 0; nt < 2; ++nt) acc_s[mt][nt] = zz;

    // ---- S rounds ks=0..3 (K=256): A from regs, only bq2 from LDS ----
    #pragma unroll
    for (int ks = 0; ks < 4; ++ks) {
      char* sl = (ks & 1) ? slabB : slabA;
      waitv<4>();                          // this round done; next in flight
      #pragma unroll
      for (int kq = 0; kq < 2; ++kq) {
        int sw = ((kq * 4 + q) ^ (i & 7)) * 16;
        bf8 bq2[2];
        #pragma unroll
        for (int nt = 0; nt < 2; ++nt)
          bq2[nt] = *(const bf8*)(sl + (nt * 16 + i) * 128 + sw);
        __builtin_amdgcn_s_setprio(1);
        #pragma unroll
        for (int mt = 0; mt < 4; ++mt)
          #pragma unroll
          for (int nt = 0; nt < 2; ++nt)
            acc_s[mt][nt] = MFMA16(af_r[ks][kq][mt], bq2[nt], acc_s[mt][nt]);
        __builtin_amdgcn_s_setprio(0);
      }
      lgkm0();                             // slab reads retired before refill
      if (ks < 2) stageS(c, ks + 2, sl);   // rounds 2,3: S ks+2
      else        stageV(c, 0, ks - 2, sl);// rounds 4,5: PV ks2=0, halves 0,1
    }

    // ---- exp -> P panels (PV rounds 4,5 in flight under this VALU work) ----
    barrier_relaxed();                     // prev chunk's P readers all done
    #pragma unroll
    for (int nt = 0; nt < 2; ++nt) {
      float snv = sn[c][nt];
      int nl = w * 32 + nt * 16 + i;
      char* pbase = Ppan + (nl >> 6) * 8192 + (nl & 7) * 2;
      int gchunk = (nl >> 3) & 7;
      #pragma unroll
      for (int mt = 0; mt < 4; ++mt)
        #pragma unroll
        for (int r = 0; r < 4; ++r) {
          int ml = mt * 16 + q * 4 + r;
          float p = __expf(acc_s[mt][nt][r] * sc1 - sm2[mt][r] * snv);
          rowsum[mt][r] += p;
          *(short*)(pbase + ml * 128 + ((gchunk ^ (ml & 7)) * 16)) = f2bf(p);
        }
    }
    lgkm0();                               // P writes complete
    barrier_relaxed();                     // P visible to all waves

    // ---- PV rounds (ks2,h) = (0,0),(0,1),(1,0),(1,1), K=128 ----
    #pragma unroll
    for (int pv = 0; pv < 4; ++pv) {
      char* sl = (pv & 1) ? slabB : slabA;
      const int ks2 = pv >> 1, h = pv & 1;
      if (c == 7 && pv == 3) waitv<0>(); else waitv<4>();
      #pragma unroll
      for (int kq = 0; kq < 2; ++kq) {
        int sw = ((kq * 4 + q) ^ (i & 7)) * 16;
        bf8 ap[4], bv2[2];
        #pragma unroll
        for (int mt = 0; mt < 4; ++mt)
          ap[mt] = *(const bf8*)(Ppan + ks2 * 8192 + (mt * 16 + i) * 128 + sw);
        #pragma unroll
        for (int u = 0; u < 2; ++u)
          bv2[u] = *(const bf8*)(sl + (u * 16 + i) * 128 + sw);
        __builtin_amdgcn_s_setprio(1);
        #pragma unroll
        for (int mt = 0; mt < 4; ++mt)
          #pragma unroll
          for (int u = 0; u < 2; ++u)
            acc_o[mt][h * 2 + u] = MFMA16(ap[mt], bv2[u], acc_o[mt][h * 2 + u]);
        __builtin_amdgcn_s_setprio(0);
      }
      lgkm0();
      if (pv < 2) stageV(c, 1, pv, sl);            // rounds 6,7: PV ks2=1
      else if (c < 7) stageS(c + 1, pv - 2, sl);   // next chunk S0,S1
    }
  }

  // ---- softmax rowsums: wave-reduce over i, block-reduce over waves ----
  #pragma unroll
  for (int mask = 1; mask <= 8; mask <<= 1)
    #pragma unroll
    for (int mt = 0; mt < 4; ++mt)
      #pragma unroll
      for (int r = 0; r < 4; ++r) rowsum[mt][r] += __shfl_xor(rowsum[mt][r], mask, 64);
  __syncthreads();                               // all PV P-reads done; reuse Ppan
  float* rs = (float*)Ppan;                      // [4 waves][64 m]
  if (i == 0) {
    #pragma unroll
    for (int mt = 0; mt < 4; ++mt)
      #pragma unroll
      for (int r = 0; r < 4; ++r)
        rs[w * 64 + mt * 16 + q * 4 + r] = rowsum[mt][r];
  }
  __syncthreads();
  float rinv[4][4];
  #pragma unroll
  for (int mt = 0; mt < 4; ++mt)
    #pragma unroll
    for (int r = 0; r < 4; ++r) {
      int m = mt * 16 + q * 4 + r;
      rinv[mt][r] = 1.0f / (rs[m] + rs[64 + m] + rs[128 + m] + rs[192 + m]);
    }
  // ---- normalize + OB write via per-wave LDS restage (self-contained slot) ----
  short* ob = (short*)(Bst + w * 8192);          // 256 rows x 16 shorts
  #pragma unroll
  for (int mt = 0; mt < 4; ++mt)
    #pragma unroll
    for (int ct = 0; ct < 4; ++ct)
      #pragma unroll
      for (int r = 0; r < 4; ++r)
        ob[(r * 64 + ct * 16 + i) * 16 + mt * 4 + q] =
            f2bf(acc_o[mt][ct][r] * rinv[mt][r]);
  short* obg = OB + (size_t)b * 1024 * 256;
  #pragma unroll
  for (int jj = 0; jj < 8; ++jj) {
    int lr = jj * 32 + (l >> 1), ch = l & 1;
    bf8 vv = *(const bf8*)(ob + lr * 16 + ch * 8);
    int rr = lr >> 6, cc = lr & 63;
    *(bf8*)(obg + ((size_t)(rr * 256 + w * 64 + cc)) * 256 + bm * 16 + ch * 8) = vv;
  }
}

// ---------------- K3: output projection + bias + residual ----------------
__global__ __launch_bounds__(256, 2) void k3_out(const short* __restrict__ Wo_bf,
                                                 const short* __restrict__ OB,
                                                 const float* __restrict__ bo,
                                                 const float* __restrict__ x,
                                                 float* __restrict__ out) {
  __shared__ __attribute__((aligned(16))) char smem[65536];
  f32x4 acc[4][4];
  int bm = blockIdx.x, bn = blockIdx.y, b = blockIdx.z;
  gemm_core(Wo_bf + (size_t)bm * 128 * 256,
            OB + ((size_t)b * 1024 + bn * 128) * 256, 256, 256, 4, smem, acc);
  int tid = threadIdx.x;
  int w = tid >> 6, l = tid & 63, q = l >> 4, i = l & 15;
  int wm = w & 1, wn = w >> 1;
  int oloc = bm * 128 + wm * 64, sploc = bn * 128 + wn * 64;
  #pragma unroll
  for (int mt = 0; mt < 4; ++mt)
    #pragma unroll
    for (int r = 0; r < 4; ++r) {
      int o = oloc + mt * 16 + q * 4 + r;
      float bias = bo[o];
      #pragma unroll
      for (int nt = 0; nt < 4; ++nt) {
        int sp = sploc + nt * 16 + i;
        size_t idx = ((size_t)b * 512 + o) * 1024 + sp;
        out[idx] = acc[mt][nt][r] + bias + x[idx];
      }
    }
}

extern "C" void kernel_launch(void* const* d_in, const int* in_sizes, int n_in,
                              void* d_out, int out_size, void* d_ws, size_t ws_size,
                              hipStream_t stream) {
  (void)in_sizes; (void)n_in; (void)out_size; (void)ws_size;
  const float* x  = (const float*)d_in[0];
  const float* Wk = (const float*)d_in[1];
  const float* bk = (const float*)d_in[2];
  const float* Wv = (const float*)d_in[3];
  const float* bv = (const float*)d_in[4];
  const float* Wo = (const float*)d_in[5];
  const float* bo = (const float*)d_in[6];
  float* out = (float*)d_out;
  char* ws = (char*)d_ws;

  // ws layout (~68.5 MB), time-aliased:
  //   [0,32M)   : xT (P0->K1, 32 MB) then OB (K2->K3, 16 MB)
  //   [32M,48M) : kT (K1->K2)
  //   [48M,64M) : vT (K1->K2)
  //   [64M,...) : weights + reduction buffers
  short* xT     = (short*)(ws);
  short* OB     = (short*)(ws);
  short* kTb    = (short*)(ws + 33554432);
  short* vTb    = (short*)(ws + 50331648);
  short* Wkv_bf = (short*)(ws + 67108864);
  short* Wo_bf  = (short*)(ws + 67633152);
  float* s_part = (float*)(ws + 67895296);

  p0_xpose<<<dim3(8, 16, 32), 256, 0, stream>>>(x, xT);
  w0_weights<<<1536, 256, 0, stream>>>(Wk, Wv, Wo, Wkv_bf, Wo_bf);
  k1_kv<<<dim3(256, 4), 256, 0, stream>>>(xT, Wkv_bf, bk, bv, kTb, vTb, s_part);
  k2_fused<<<dim3(512), 256, 0, stream>>>(kTb, vTb, s_part, OB);
  k3_out<<<dim3(4, 8, 32), 256, 0, stream>>>(Wo_bf, OB, bo, x, out);
}

// Round 4
// 263.175 us; speedup vs baseline: 1.2675x; 1.2675x over previous
//
#include <hip/hip_runtime.h>

// B=32, C=512, c2=256, M=1024. All GEMMs bf16 MFMA (fp32 accum), m97-style:
// 128x128 (or fused) tiles, BK=64, global_load_lds(16B) staging, XOR-swizzled
// chunks.
//
// P0 : x[b][c][sp] fp32 -> xT[b*1024+sp][c] bf16
// W0 : weight casts (Wkv = [Wk;Wv] 512x512, Wo 512x256)
// K1 : [32768x512]x[512x512]: k-half -> kT[m][c] + row-sum partials,
//      v-half -> vT[b][c][n] (reshape-permuted)
// K2 : FUSED flash-style attention per (64-row m-stripe, batch), v4:
//      HALF of the chunk-invariant A-stripe in 16 NAMED bf8 registers
//      (spill-proof: no arrays -> no SROA demotion), other half in 16KB
//      Apan; combined row-sums (ex-K1b) in a 4KB LDS table; wave-self-
//      contained 4KB staging rounds, counted vmcnt(4), 2 raw s_barriers
//      per chunk, setprio, bijective XCD swizzle (4 batches/XCD).
// K3 : out = Wo @ O2 + bo + x (fp32), B = OB (k-major)

typedef short bf8 __attribute__((ext_vector_type(8)));
typedef float f32x4 __attribute__((ext_vector_type(4)));

#define MFMA16(a, b, c) __builtin_amdgcn_mfma_f32_16x16x32_bf16((a), (b), (c), 0, 0, 0)

__device__ __forceinline__ short f2bf(float x) {
  unsigned u = __float_as_uint(x);
  u += 0x7fffu + ((u >> 16) & 1u);   // RNE, finite inputs
  return (short)(u >> 16);
}

__device__ __forceinline__ void gll16(const short* g, void* l) {
  __builtin_amdgcn_global_load_lds(
      (const __attribute__((address_space(1))) unsigned int*)g,
      (__attribute__((address_space(3))) unsigned int*)l, 16, 0, 0);
}

__device__ __forceinline__ void lgkm0() {
  asm volatile("s_waitcnt lgkmcnt(0)" ::: "memory");
}
template <int N>
__device__ __forceinline__ void waitv() {
  static_assert(N == 0 || N == 4 || N == 8, "bad vmcnt");
  if constexpr (N == 0) asm volatile("s_waitcnt vmcnt(0)" ::: "memory");
  else if constexpr (N == 4) asm volatile("s_waitcnt vmcnt(4)" ::: "memory");
  else asm volatile("s_waitcnt vmcnt(8)" ::: "memory");
}
__device__ __forceinline__ void barrier_relaxed() {
  asm volatile("" ::: "memory");
  __builtin_amdgcn_s_barrier();
  asm volatile("" ::: "memory");
}

// S-phase helper: one kq quarter, A from 4 named regs, B from wave slab.
// base = slab + i*128, sw = swizzled byte offset for this kq.
__device__ __forceinline__ void s_kq(const char* base, int sw,
                                     bf8 A0, bf8 A1, bf8 A2, bf8 A3,
                                     f32x4 (&acc)[4][2]) {
  bf8 b0 = *(const bf8*)(base + sw);
  bf8 b1 = *(const bf8*)(base + 2048 + sw);
  __builtin_amdgcn_s_setprio(1);
  acc[0][0] = MFMA16(A0, b0, acc[0][0]);
  acc[0][1] = MFMA16(A0, b1, acc[0][1]);
  acc[1][0] = MFMA16(A1, b0, acc[1][0]);
  acc[1][1] = MFMA16(A1, b1, acc[1][1]);
  acc[2][0] = MFMA16(A2, b0, acc[2][0]);
  acc[2][1] = MFMA16(A2, b1, acc[2][1]);
  acc[3][0] = MFMA16(A3, b0, acc[3][0]);
  acc[3][1] = MFMA16(A3, b1, acc[3][1]);
  __builtin_amdgcn_s_setprio(0);
}

// S-phase helper: one kq quarter, A from LDS panel (ap = panel + i*128).
__device__ __forceinline__ void s_kq_lds(const char* base, const char* ap,
                                         int sw, f32x4 (&acc)[4][2]) {
  bf8 A0 = *(const bf8*)(ap + sw);
  bf8 A1 = *(const bf8*)(ap + 2048 + sw);
  bf8 A2 = *(const bf8*)(ap + 4096 + sw);
  bf8 A3 = *(const bf8*)(ap + 6144 + sw);
  s_kq(base, sw, A0, A1, A2, A3, acc);
}

// ---- shared GEMM core (R1-proven): C[128][128] tile, single 32KB buffer ----
__device__ __forceinline__ void gemm_core(const short* __restrict__ A,
                                          const short* __restrict__ B,
                                          int ldA, int ldB, int ksteps,
                                          char* smem, f32x4 acc[4][4]) {
  const int tid = threadIdx.x;
  const int w = tid >> 6, l = tid & 63;
  const int q = l >> 4, i = l & 15;
  const int wm = w & 1, wn = w >> 1;
  const int srow = l >> 3;
  const int gcol = ((l & 7) ^ srow) * 8;        // swizzled 16B chunk (shorts)
  f32x4 zz = {0.f, 0.f, 0.f, 0.f};
  #pragma unroll
  for (int mt = 0; mt < 4; ++mt)
    #pragma unroll
    for (int nt = 0; nt < 4; ++nt) acc[mt][nt] = zz;

  for (int ks = 0; ks < ksteps; ++ks) {
    __syncthreads();                            // LDS free (prev reads done)
    const short* Ak = A + ks * 64 + gcol;
    const short* Bk = B + ks * 64 + gcol;
    #pragma unroll
    for (int j = 0; j < 4; ++j) {
      int s = w * 4 + j;
      size_t row = (size_t)(s * 8 + srow);
      gll16(Ak + row * ldA, smem + s * 1024);
      gll16(Bk + row * ldB, smem + 16384 + s * 1024);
    }
    __syncthreads();                            // staged data visible
    #pragma unroll
    for (int kq = 0; kq < 2; ++kq) {
      int sw = ((kq * 4 + q) ^ (i & 7)) * 16;   // swizzled read offset (bytes)
      bf8 af[4], bq[4];
      #pragma unroll
      for (int mt = 0; mt < 4; ++mt)
        af[mt] = *(const bf8*)(smem + (wm * 64 + mt * 16 + i) * 128 + sw);
      #pragma unroll
      for (int nt = 0; nt < 4; ++nt)
        bq[nt] = *(const bf8*)(smem + 16384 + (wn * 64 + nt * 16 + i) * 128 + sw);
      #pragma unroll
      for (int mt = 0; mt < 4; ++mt)
        #pragma unroll
        for (int nt = 0; nt < 4; ++nt)
          acc[mt][nt] = MFMA16(af[mt], bq[nt], acc[mt][nt]);
    }
  }
}

// ---------------- P0: transpose + convert x ----------------
__global__ __launch_bounds__(256) void p0_xpose(const float* __restrict__ x,
                                                short* __restrict__ xT) {
  __shared__ float lds[64][65];
  int cb = blockIdx.x, sb = blockIdx.y, b = blockIdx.z;
  int t = threadIdx.x;
  int c0 = cb * 64, sp0 = sb * 64;
  const float4* x4 = reinterpret_cast<const float4*>(x);
  #pragma unroll
  for (int j = 0; j < 4; ++j) {
    int lin = t + 256 * j;
    int cl = lin >> 4, s4 = lin & 15;
    float4 v = x4[(((size_t)b * 512 + c0 + cl) * 1024 + sp0 + s4 * 4) >> 2];
    lds[cl][s4 * 4 + 0] = v.x; lds[cl][s4 * 4 + 1] = v.y;
    lds[cl][s4 * 4 + 2] = v.z; lds[cl][s4 * 4 + 3] = v.w;
  }
  __syncthreads();
  int spl = t >> 2, cs = (t & 3) * 16;
  bf8 o0, o1;
  #pragma unroll
  for (int j = 0; j < 8; ++j) o0[j] = f2bf(lds[cs + j][spl]);
  #pragma unroll
  for (int j = 0; j < 8; ++j) o1[j] = f2bf(lds[cs + 8 + j][spl]);
  size_t base = ((size_t)b * 1024 + sp0 + spl) * 512 + c0 + cs;
  *reinterpret_cast<bf8*>(xT + base) = o0;
  *reinterpret_cast<bf8*>(xT + base + 8) = o1;
}

// ---------------- W0: weight casts ----------------
__global__ __launch_bounds__(256) void w0_weights(const float* __restrict__ Wk,
                                                  const float* __restrict__ Wv,
                                                  const float* __restrict__ Wo,
                                                  short* __restrict__ Wkv_bf,
                                                  short* __restrict__ Wo_bf) {
  int g = blockIdx.x * 256 + threadIdx.x;
  if (g < 262144) {
    int o = g >> 9, c = g & 511;
    float v = (o < 256) ? Wk[o * 512 + c] : Wv[(o - 256) * 512 + c];
    Wkv_bf[g] = f2bf(v);
  } else {
    int i2 = g - 262144;
    Wo_bf[i2] = f2bf(Wo[i2]);
  }
}

// ---------------- K1: fused k/v projection GEMM ----------------
__global__ __launch_bounds__(256, 2) void k1_kv(const short* __restrict__ xT,
                                                const short* __restrict__ Wkv,
                                                const float* __restrict__ bk,
                                                const float* __restrict__ bv,
                                                short* __restrict__ kT,
                                                short* __restrict__ vT,
                                                float* __restrict__ s_part) {
  __shared__ __attribute__((aligned(16))) char smem[32768];
  f32x4 acc[4][4];
  int bm = blockIdx.x, bn = blockIdx.y;
  gemm_core(xT + (size_t)bm * 128 * 512, Wkv + (size_t)bn * 128 * 512,
            512, 512, 8, smem, acc);
  int tid = threadIdx.x;
  int w = tid >> 6, l = tid & 63, q = l >> 4, i = l & 15;
  int wm = w & 1, wn = w >> 1;
  int mbase = bm * 128 + wm * 64;
  int nbase = bn * 128 + wn * 64;
  if (bn < 2) {                                  // k half
    float rp[4][4];
    #pragma unroll
    for (int mt = 0; mt < 4; ++mt)
      #pragma unroll
      for (int r = 0; r < 4; ++r) rp[mt][r] = 0.f;
    #pragma unroll
    for (int mt = 0; mt < 4; ++mt)
      #pragma unroll
      for (int nt = 0; nt < 4; ++nt) {
        float bias = bk[nbase + nt * 16 + i];
        #pragma unroll
        for (int r = 0; r < 4; ++r) {
          float val = acc[mt][nt][r] + bias;
          int mg = mbase + mt * 16 + q * 4 + r;
          kT[(size_t)mg * 256 + nbase + nt * 16 + i] = f2bf(val);
          rp[mt][r] += val;
        }
      }
    #pragma unroll
    for (int mask = 1; mask <= 8; mask <<= 1)
      #pragma unroll
      for (int mt = 0; mt < 4; ++mt)
        #pragma unroll
        for (int r = 0; r < 4; ++r) rp[mt][r] += __shfl_xor(rp[mt][r], mask, 64);
    if (i == 0) {
      int pg = bn * 2 + wn;
      #pragma unroll
      for (int mt = 0; mt < 4; ++mt)
        #pragma unroll
        for (int r = 0; r < 4; ++r)
          s_part[pg * 32768 + mbase + mt * 16 + q * 4 + r] = rp[mt][r];
    }
  } else {                                       // v half -> vT permuted
    #pragma unroll
    for (int mt = 0; mt < 4; ++mt)
      #pragma unroll
      for (int nt = 0; nt < 4; ++nt) {
        int o2 = nbase + nt * 16 + i - 256;
        float bias = bv[o2];
        #pragma unroll
        for (int r = 0; r < 4; ++r) {
          float val = acc[mt][nt][r] + bias;
          int mg = mbase + mt * 16 + q * 4 + r;
          int b = mg >> 10, sp = mg & 1023;
          vT[((size_t)b * 256 + (sp & 255)) * 1024 + 4 * o2 + (sp >> 8)] = f2bf(val);
        }
      }
  }
}

// ---------------- K2 v4: fused gram -> softmax -> PV -> OB ----------------
// LDS: Apan 16K (ks=2,3 panels) | Ppan 16K | Bst 32K (2 bufs x 4 waves x
// 4KB; also prologue A ks=0,1 staging) | sLDS 4K (combined row-sums).
// ks=0,1 A-fragments in 16 NAMED bf8 registers for all 8 chunks.
__global__ __launch_bounds__(256, 2) void k2_fused(const short* __restrict__ kT,
                                                   const short* __restrict__ vT,
                                                   const float* __restrict__ s_part,
                                                   short* __restrict__ OB) {
  __shared__ __attribute__((aligned(16))) char smem[69632];
  char* Apan = smem;            // 16 KB: panels for ks=2,3
  char* Ppan = smem + 16384;    // 16 KB: 2 panels x (64 rows x 128 B)
  char* Bst  = smem + 32768;    // 32 KB: 2 bufs x 4 waves x 4 KB
  float* sLDS = (float*)(smem + 65536);  // 4 KB: combined row-sums [1024]

  const int id = blockIdx.x;
  const int xcd = id & 7, slot = id >> 3;
  const int b  = xcd * 4 + (slot >> 4);   // 4 batches per XCD (L2-resident)
  const int bm = slot & 15;

  const int tid = threadIdx.x;
  const int w = tid >> 6, l = tid & 63;
  const int q = l >> 4, i = l & 15;
  const int srow = l >> 3;
  const int gcol = ((l & 7) ^ srow) * 8;

  const short* kTb = kT + (size_t)b * 1024 * 256;
  const short* vTb = vT + (size_t)b * 256 * 1024;

  char* slabA = Bst + w * 4096;            // even rounds
  char* slabB = Bst + 16384 + w * 4096;    // odd rounds

  const float sc1 = 1.0f / 16384.0f;             // (1/M)/16
  const float sc2 = 1.0f / 16777216.0f;          // (1/M^2)/16

  // ---- prologue: issue A staging (ks01 -> Bst, ks23 -> Apan) ----
  {
    const short* Am = kTb + (size_t)bm * 64 * 256;
    #pragma unroll
    for (int ks = 0; ks < 2; ++ks)
      #pragma unroll
      for (int j2 = 0; j2 < 2; ++j2) {
        int s2 = w * 2 + j2;
        gll16(Am + (size_t)(s2 * 8 + srow) * 256 + ks * 64 + gcol,
              Bst + ks * 8192 + s2 * 1024);
      }
    #pragma unroll
    for (int ks = 2; ks < 4; ++ks)
      #pragma unroll
      for (int j2 = 0; j2 < 2; ++j2) {
        int s2 = w * 2 + j2;
        gll16(Am + (size_t)(s2 * 8 + srow) * 256 + ks * 64 + gcol,
              Apan + (ks - 2) * 8192 + s2 * 1024);
      }
  }

  // ---- combined row-sums (ex-K1b) -> sLDS[1024] ----
  const int mglob = b * 1024;
  {
    const float4* p0 = (const float4*)(s_part + mglob) + tid;
    const float4* p1 = (const float4*)(s_part + 32768 + mglob) + tid;
    const float4* p2 = (const float4*)(s_part + 65536 + mglob) + tid;
    const float4* p3 = (const float4*)(s_part + 98304 + mglob) + tid;
    float4 v0 = *p0, v1 = *p1, v2 = *p2, v3 = *p3;
    float4 s;
    s.x = v0.x + v1.x + v2.x + v3.x;
    s.y = v0.y + v1.y + v2.y + v3.y;
    s.z = v0.z + v1.z + v2.z + v3.z;
    s.w = v0.w + v1.w + v2.w + v3.w;
    ((float4*)sLDS)[tid] = s;
  }

  waitv<0>();                              // all prologue VMEM retired
  lgkm0();                                 // sLDS writes complete
  barrier_relaxed();                       // A ks01/ks23 + sLDS visible

  // ---- one-time reg-fill of ks=0,1 A-fragments (16 NAMED bf8) ----
  const int sw0 = (q ^ (i & 7)) * 16;            // kq=0
  const int sw1 = ((4 + q) ^ (i & 7)) * 16;      // kq=1
  const char* fb0 = Bst + i * 128;               // ks=0 panel base
  const char* fb1 = Bst + 8192 + i * 128;        // ks=1 panel base
  bf8 a000 = *(const bf8*)(fb0 + sw0);
  bf8 a001 = *(const bf8*)(fb0 + 2048 + sw0);
  bf8 a002 = *(const bf8*)(fb0 + 4096 + sw0);
  bf8 a003 = *(const bf8*)(fb0 + 6144 + sw0);
  bf8 a010 = *(const bf8*)(fb0 + sw1);
  bf8 a011 = *(const bf8*)(fb0 + 2048 + sw1);
  bf8 a012 = *(const bf8*)(fb0 + 4096 + sw1);
  bf8 a013 = *(const bf8*)(fb0 + 6144 + sw1);
  bf8 a100 = *(const bf8*)(fb1 + sw0);
  bf8 a101 = *(const bf8*)(fb1 + 2048 + sw0);
  bf8 a102 = *(const bf8*)(fb1 + 4096 + sw0);
  bf8 a103 = *(const bf8*)(fb1 + 6144 + sw0);
  bf8 a110 = *(const bf8*)(fb1 + sw1);
  bf8 a111 = *(const bf8*)(fb1 + 2048 + sw1);
  bf8 a112 = *(const bf8*)(fb1 + 4096 + sw1);
  bf8 a113 = *(const bf8*)(fb1 + 6144 + sw1);

  float sm2[4][4];
  #pragma unroll
  for (int mt = 0; mt < 4; ++mt)
    #pragma unroll
    for (int r = 0; r < 4; ++r)
      sm2[mt][r] = sLDS[bm * 64 + mt * 16 + q * 4 + r] * sc2;

  lgkm0();                                 // reg-fill retired before Bst reuse
  barrier_relaxed();                       // all waves done reading Bst ks01

  // staging helpers: each wave stages exactly the rows its MFMAs read
  auto stageS = [&](int c, int ks, char* sl) {
    const short* Bn = kTb + (size_t)c * 128 * 256 + ks * 64 + gcol;
    #pragma unroll
    for (int j = 0; j < 4; ++j)
      gll16(Bn + (size_t)(w * 32 + j * 8 + srow) * 256, sl + j * 1024);
  };
  auto stageV = [&](int c, int ks2, int h, char* sl) {
    const short* Vn = vTb + c * 128 + ks2 * 64 + gcol;
    #pragma unroll
    for (int j = 0; j < 4; ++j)
      gll16(Vn + (size_t)(w * 64 + h * 32 + j * 8 + srow) * 1024, sl + j * 1024);
  };

  stageS(0, 0, slabA);                     // round 0
  stageS(0, 1, slabB);                     // round 1

  f32x4 zz = {0.f, 0.f, 0.f, 0.f};
  f32x4 acc_o[4][4];
  float rowsum[4][4];
  #pragma unroll
  for (int mt = 0; mt < 4; ++mt)
    #pragma unroll
    for (int ct = 0; ct < 4; ++ct) acc_o[mt][ct] = zz;
  #pragma unroll
  for (int mt = 0; mt < 4; ++mt)
    #pragma unroll
    for (int r = 0; r < 4; ++r) rowsum[mt][r] = 0.f;

  const char* sA = slabA + i * 128;        // per-wave slab read bases
  const char* sB = slabB + i * 128;
  const char* ap0 = Apan + i * 128;        // ks=2 panel
  const char* ap1 = Apan + 8192 + i * 128; // ks=3 panel

  #pragma unroll
  for (int c = 0; c < 8; ++c) {
    f32x4 acc_s[4][2];
    #pragma unroll
    for (int mt = 0; mt < 4; ++mt)
      #pragma unroll
      for (int nt = 0; nt < 2; ++nt) acc_s[mt][nt] = zz;

    // ---- S rounds (K=256): ks=0,1 A from regs; ks=2,3 A from Apan ----
    waitv<4>();
    s_kq(sA, sw0, a000, a001, a002, a003, acc_s);
    s_kq(sA, sw1, a010, a011, a012, a013, acc_s);
    lgkm0();
    stageS(c, 2, slabA);

    waitv<4>();
    s_kq(sB, sw0, a100, a101, a102, a103, acc_s);
    s_kq(sB, sw1, a110, a111, a112, a113, acc_s);
    lgkm0();
    stageS(c, 3, slabB);

    waitv<4>();
    s_kq_lds(sA, ap0, sw0, acc_s);
    s_kq_lds(sA, ap0, sw1, acc_s);
    lgkm0();
    stageV(c, 0, 0, slabA);

    waitv<4>();
    s_kq_lds(sB, ap1, sw0, acc_s);
    s_kq_lds(sB, ap1, sw1, acc_s);
    lgkm0();
    stageV(c, 0, 1, slabB);

    // ---- exp -> P panels (PV rounds 4,5 in flight under this VALU work) ----
    barrier_relaxed();                     // prev chunk's P readers all done
    float snv0 = sLDS[c * 128 + w * 32 + i];
    float snv1 = sLDS[c * 128 + w * 32 + 16 + i];
    #pragma unroll
    for (int nt = 0; nt < 2; ++nt) {
      float snv = nt ? snv1 : snv0;
      int nl = w * 32 + nt * 16 + i;
      char* pbase = Ppan + (nl >> 6) * 8192 + (nl & 7) * 2;
      int gchunk = (nl >> 3) & 7;
      #pragma unroll
      for (int mt = 0; mt < 4; ++mt)
        #pragma unroll
        for (int r = 0; r < 4; ++r) {
          int ml = mt * 16 + q * 4 + r;
          float p = __expf(acc_s[mt][nt][r] * sc1 - sm2[mt][r] * snv);
          rowsum[mt][r] += p;
          *(short*)(pbase + ml * 128 + ((gchunk ^ (ml & 7)) * 16)) = f2bf(p);
        }
    }
    lgkm0();                               // P writes complete
    barrier_relaxed();                     // P visible to all waves

    // ---- PV rounds (ks2,h) = (0,0),(0,1),(1,0),(1,1), K=128 ----
    #pragma unroll
    for (int pv = 0; pv < 4; ++pv) {
      char* sl = (pv & 1) ? slabB : slabA;
      const int ks2 = pv >> 1, h = pv & 1;
      if (c == 7 && pv == 3) waitv<0>(); else waitv<4>();
      #pragma unroll
      for (int kq = 0; kq < 2; ++kq) {
        int sw = ((kq * 4 + q) ^ (i & 7)) * 16;
        bf8 ap[4], bv2[2];
        #pragma unroll
        for (int mt = 0; mt < 4; ++mt)
          ap[mt] = *(const bf8*)(Ppan + ks2 * 8192 + (mt * 16 + i) * 128 + sw);
        #pragma unroll
        for (int u = 0; u < 2; ++u)
          bv2[u] = *(const bf8*)(sl + (u * 16 + i) * 128 + sw);
        __builtin_amdgcn_s_setprio(1);
        #pragma unroll
        for (int mt = 0; mt < 4; ++mt)
          #pragma unroll
          for (int u = 0; u < 2; ++u)
            acc_o[mt][h * 2 + u] = MFMA16(ap[mt], bv2[u], acc_o[mt][h * 2 + u]);
        __builtin_amdgcn_s_setprio(0);
      }
      lgkm0();
      if (pv < 2) stageV(c, 1, pv, sl);            // rounds 6,7: PV ks2=1
      else if (c < 7) stageS(c + 1, pv - 2, sl);   // next chunk S0,S1
    }
  }

  // ---- softmax rowsums: wave-reduce over i, block-reduce over waves ----
  #pragma unroll
  for (int mask = 1; mask <= 8; mask <<= 1)
    #pragma unroll
    for (int mt = 0; mt < 4; ++mt)
      #pragma unroll
      for (int r = 0; r < 4; ++r) rowsum[mt][r] += __shfl_xor(rowsum[mt][r], mask, 64);
  __syncthreads();                               // all PV P-reads done; reuse Ppan
  float* rs = (float*)Ppan;                      // [4 waves][64 m]
  if (i == 0) {
    #pragma unroll
    for (int mt = 0; mt < 4; ++mt)
      #pragma unroll
      for (int r = 0; r < 4; ++r)
        rs[w * 64 + mt * 16 + q * 4 + r] = rowsum[mt][r];
  }
  __syncthreads();
  float rinv[4][4];
  #pragma unroll
  for (int mt = 0; mt < 4; ++mt)
    #pragma unroll
    for (int r = 0; r < 4; ++r) {
      int m = mt * 16 + q * 4 + r;
      rinv[mt][r] = 1.0f / (rs[m] + rs[64 + m] + rs[128 + m] + rs[192 + m]);
    }
  // ---- normalize + OB write via per-wave LDS restage (self-contained slot) ----
  short* ob = (short*)(Bst + w * 8192);          // 256 rows x 16 shorts
  #pragma unroll
  for (int mt = 0; mt < 4; ++mt)
    #pragma unroll
    for (int ct = 0; ct < 4; ++ct)
      #pragma unroll
      for (int r = 0; r < 4; ++r)
        ob[(r * 64 + ct * 16 + i) * 16 + mt * 4 + q] =
            f2bf(acc_o[mt][ct][r] * rinv[mt][r]);
  short* obg = OB + (size_t)b * 1024 * 256;
  #pragma unroll
  for (int jj = 0; jj < 8; ++jj) {
    int lr = jj * 32 + (l >> 1), ch = l & 1;
    bf8 vv = *(const bf8*)(ob + lr * 16 + ch * 8);
    int rr = lr >> 6, cc = lr & 63;
    *(bf8*)(obg + ((size_t)(rr * 256 + w * 64 + cc)) * 256 + bm * 16 + ch * 8) = vv;
  }
}

// ---------------- K3: output projection + bias + residual ----------------
__global__ __launch_bounds__(256, 2) void k3_out(const short* __restrict__ Wo_bf,
                                                 const short* __restrict__ OB,
                                                 const float* __restrict__ bo,
                                                 const float* __restrict__ x,
                                                 float* __restrict__ out) {
  __shared__ __attribute__((aligned(16))) char smem[32768];
  f32x4 acc[4][4];
  int bm = blockIdx.x, bn = blockIdx.y, b = blockIdx.z;
  gemm_core(Wo_bf + (size_t)bm * 128 * 256,
            OB + ((size_t)b * 1024 + bn * 128) * 256, 256, 256, 4, smem, acc);
  int tid = threadIdx.x;
  int w = tid >> 6, l = tid & 63, q = l >> 4, i = l & 15;
  int wm = w & 1, wn = w >> 1;
  int oloc = bm * 128 + wm * 64, sploc = bn * 128 + wn * 64;
  #pragma unroll
  for (int mt = 0; mt < 4; ++mt)
    #pragma unroll
    for (int r = 0; r < 4; ++r) {
      int o = oloc + mt * 16 + q * 4 + r;
      float bias = bo[o];
      #pragma unroll
      for (int nt = 0; nt < 4; ++nt) {
        int sp = sploc + nt * 16 + i;
        size_t idx = ((size_t)b * 512 + o) * 1024 + sp;
        out[idx] = acc[mt][nt][r] + bias + x[idx];
      }
    }
}

extern "C" void kernel_launch(void* const* d_in, const int* in_sizes, int n_in,
                              void* d_out, int out_size, void* d_ws, size_t ws_size,
                              hipStream_t stream) {
  (void)in_sizes; (void)n_in; (void)out_size; (void)ws_size;
  const float* x  = (const float*)d_in[0];
  const float* Wk = (const float*)d_in[1];
  const float* bk = (const float*)d_in[2];
  const float* Wv = (const float*)d_in[3];
  const float* bv = (const float*)d_in[4];
  const float* Wo = (const float*)d_in[5];
  const float* bo = (const float*)d_in[6];
  float* out = (float*)d_out;
  char* ws = (char*)d_ws;

  // ws layout (~68.5 MB), time-aliased:
  //   [0,32M)   : xT (P0->K1, 32 MB) then OB (K2->K3, 16 MB)
  //   [32M,48M) : kT (K1->K2)
  //   [48M,64M) : vT (K1->K2)
  //   [64M,...) : weights + reduction buffers
  short* xT     = (short*)(ws);
  short* OB     = (short*)(ws);
  short* kTb    = (short*)(ws + 33554432);
  short* vTb    = (short*)(ws + 50331648);
  short* Wkv_bf = (short*)(ws + 67108864);
  short* Wo_bf  = (short*)(ws + 67633152);
  float* s_part = (float*)(ws + 67895296);

  p0_xpose<<<dim3(8, 16, 32), 256, 0, stream>>>(x, xT);
  w0_weights<<<1536, 256, 0, stream>>>(Wk, Wv, Wo, Wkv_bf, Wo_bf);
  k1_kv<<<dim3(256, 4), 256, 0, stream>>>(xT, Wkv_bf, bk, bv, kTb, vTb, s_part);
  k2_fused<<<dim3(512), 256, 0, stream>>>(kTb, vTb, s_part, OB);
  k3_out<<<dim3(4, 8, 32), 256, 0, stream>>>(Wo_bf, OB, bo, x, out);
}

// Round 5
// 236.983 us; speedup vs baseline: 1.4076x; 1.1105x over previous
//
#include <hip/hip_runtime.h>

// B=32, C=512, c2=256, M=1024. All GEMMs bf16 MFMA (fp32 accum), m97-style:
// 128x128 (or fused) tiles, BK=64, global_load_lds(16B) staging, XOR-swizzled
// chunks.
//
// P0 : x[b][c][sp] fp32 -> xT[b*1024+sp][c] bf16
// W0 : weight casts (Wkv = [Wk;Wv] 512x512, Wo 512x256)
// K1 : [32768x512]x[512x512]: k-half -> kT[m][c] (LDS-restaged coalesced
//      16B stores) + row-sum partials, v-half -> vT (inherent 2B scatter)
// K2 : FUSED flash-style attention per (64-row m-stripe, batch) — R1-proven
//      v2 pipeline (A panels in LDS, wave-self-contained 4KB staging rounds,
//      counted vmcnt(4), 2 raw s_barriers/chunk, setprio, XCD swizzle) +
//      K1b row-sum combine folded into prologue (register sums).
// K3 : out = Wo @ O2 + bo + x, epilogue LDS-restaged to float4 loads/stores.

typedef short bf8 __attribute__((ext_vector_type(8)));
typedef float f32x4 __attribute__((ext_vector_type(4)));

#define MFMA16(a, b, c) __builtin_amdgcn_mfma_f32_16x16x32_bf16((a), (b), (c), 0, 0, 0)

__device__ __forceinline__ short f2bf(float x) {
  unsigned u = __float_as_uint(x);
  u += 0x7fffu + ((u >> 16) & 1u);   // RNE, finite inputs
  return (short)(u >> 16);
}

__device__ __forceinline__ void gll16(const short* g, void* l) {
  __builtin_amdgcn_global_load_lds(
      (const __attribute__((address_space(1))) unsigned int*)g,
      (__attribute__((address_space(3))) unsigned int*)l, 16, 0, 0);
}

__device__ __forceinline__ void lgkm0() {
  asm volatile("s_waitcnt lgkmcnt(0)" ::: "memory");
}
template <int N>
__device__ __forceinline__ void waitv() {
  static_assert(N == 0 || N == 4 || N == 8, "bad vmcnt");
  if constexpr (N == 0) asm volatile("s_waitcnt vmcnt(0)" ::: "memory");
  else if constexpr (N == 4) asm volatile("s_waitcnt vmcnt(4)" ::: "memory");
  else asm volatile("s_waitcnt vmcnt(8)" ::: "memory");
}
__device__ __forceinline__ void barrier_relaxed() {
  asm volatile("" ::: "memory");
  __builtin_amdgcn_s_barrier();
  asm volatile("" ::: "memory");
}

// ---- shared GEMM core (R1-proven): C[128][128] tile, single 32KB buffer ----
__device__ __forceinline__ void gemm_core(const short* __restrict__ A,
                                          const short* __restrict__ B,
                                          int ldA, int ldB, int ksteps,
                                          char* smem, f32x4 acc[4][4]) {
  const int tid = threadIdx.x;
  const int w = tid >> 6, l = tid & 63;
  const int q = l >> 4, i = l & 15;
  const int wm = w & 1, wn = w >> 1;
  const int srow = l >> 3;
  const int gcol = ((l & 7) ^ srow) * 8;        // swizzled 16B chunk (shorts)
  f32x4 zz = {0.f, 0.f, 0.f, 0.f};
  #pragma unroll
  for (int mt = 0; mt < 4; ++mt)
    #pragma unroll
    for (int nt = 0; nt < 4; ++nt) acc[mt][nt] = zz;

  for (int ks = 0; ks < ksteps; ++ks) {
    __syncthreads();                            // LDS free (prev reads done)
    const short* Ak = A + ks * 64 + gcol;
    const short* Bk = B + ks * 64 + gcol;
    #pragma unroll
    for (int j = 0; j < 4; ++j) {
      int s = w * 4 + j;
      size_t row = (size_t)(s * 8 + srow);
      gll16(Ak + row * ldA, smem + s * 1024);
      gll16(Bk + row * ldB, smem + 16384 + s * 1024);
    }
    __syncthreads();                            // staged data visible
    #pragma unroll
    for (int kq = 0; kq < 2; ++kq) {
      int sw = ((kq * 4 + q) ^ (i & 7)) * 16;   // swizzled read offset (bytes)
      bf8 af[4], bq[4];
      #pragma unroll
      for (int mt = 0; mt < 4; ++mt)
        af[mt] = *(const bf8*)(smem + (wm * 64 + mt * 16 + i) * 128 + sw);
      #pragma unroll
      for (int nt = 0; nt < 4; ++nt)
        bq[nt] = *(const bf8*)(smem + 16384 + (wn * 64 + nt * 16 + i) * 128 + sw);
      #pragma unroll
      for (int mt = 0; mt < 4; ++mt)
        #pragma unroll
        for (int nt = 0; nt < 4; ++nt)
          acc[mt][nt] = MFMA16(af[mt], bq[nt], acc[mt][nt]);
    }
  }
}

// ---------------- P0: transpose + convert x ----------------
__global__ __launch_bounds__(256) void p0_xpose(const float* __restrict__ x,
                                                short* __restrict__ xT) {
  __shared__ float lds[64][65];
  int cb = blockIdx.x, sb = blockIdx.y, b = blockIdx.z;
  int t = threadIdx.x;
  int c0 = cb * 64, sp0 = sb * 64;
  const float4* x4 = reinterpret_cast<const float4*>(x);
  #pragma unroll
  for (int j = 0; j < 4; ++j) {
    int lin = t + 256 * j;
    int cl = lin >> 4, s4 = lin & 15;
    float4 v = x4[(((size_t)b * 512 + c0 + cl) * 1024 + sp0 + s4 * 4) >> 2];
    lds[cl][s4 * 4 + 0] = v.x; lds[cl][s4 * 4 + 1] = v.y;
    lds[cl][s4 * 4 + 2] = v.z; lds[cl][s4 * 4 + 3] = v.w;
  }
  __syncthreads();
  int spl = t >> 2, cs = (t & 3) * 16;
  bf8 o0, o1;
  #pragma unroll
  for (int j = 0; j < 8; ++j) o0[j] = f2bf(lds[cs + j][spl]);
  #pragma unroll
  for (int j = 0; j < 8; ++j) o1[j] = f2bf(lds[cs + 8 + j][spl]);
  size_t base = ((size_t)b * 1024 + sp0 + spl) * 512 + c0 + cs;
  *reinterpret_cast<bf8*>(xT + base) = o0;
  *reinterpret_cast<bf8*>(xT + base + 8) = o1;
}

// ---------------- W0: weight casts ----------------
__global__ __launch_bounds__(256) void w0_weights(const float* __restrict__ Wk,
                                                  const float* __restrict__ Wv,
                                                  const float* __restrict__ Wo,
                                                  short* __restrict__ Wkv_bf,
                                                  short* __restrict__ Wo_bf) {
  int g = blockIdx.x * 256 + threadIdx.x;
  if (g < 262144) {
    int o = g >> 9, c = g & 511;
    float v = (o < 256) ? Wk[o * 512 + c] : Wv[(o - 256) * 512 + c];
    Wkv_bf[g] = f2bf(v);
  } else {
    int i2 = g - 262144;
    Wo_bf[i2] = f2bf(Wo[i2]);
  }
}

// ---------------- K1: fused k/v projection GEMM ----------------
__global__ __launch_bounds__(256, 2) void k1_kv(const short* __restrict__ xT,
                                                const short* __restrict__ Wkv,
                                                const float* __restrict__ bk,
                                                const float* __restrict__ bv,
                                                short* __restrict__ kT,
                                                short* __restrict__ vT,
                                                float* __restrict__ s_part) {
  __shared__ __attribute__((aligned(16))) char smem[36864];
  f32x4 acc[4][4];
  int bm = blockIdx.x, bn = blockIdx.y;
  gemm_core(xT + (size_t)bm * 128 * 512, Wkv + (size_t)bn * 128 * 512,
            512, 512, 8, smem, acc);
  int tid = threadIdx.x;
  int w = tid >> 6, l = tid & 63, q = l >> 4, i = l & 15;
  int wm = w & 1, wn = w >> 1;
  int mbase = bm * 128 + wm * 64;
  int nbase = bn * 128 + wn * 64;
  if (bn < 2) {                                  // k half
    __syncthreads();                             // gemm tile reads done
    // per-wave LDS quadrant: 64 rows x 68 shorts (padded), 8704 B each
    short* st = (short*)smem + w * 4352;
    float rp[4][4];
    #pragma unroll
    for (int mt = 0; mt < 4; ++mt)
      #pragma unroll
      for (int r = 0; r < 4; ++r) rp[mt][r] = 0.f;
    #pragma unroll
    for (int mt = 0; mt < 4; ++mt)
      #pragma unroll
      for (int nt = 0; nt < 4; ++nt) {
        float bias = bk[nbase + nt * 16 + i];
        #pragma unroll
        for (int r = 0; r < 4; ++r) {
          float val = acc[mt][nt][r] + bias;
          st[(mt * 16 + q * 4 + r) * 68 + nt * 16 + i] = f2bf(val);
          rp[mt][r] += val;
        }
      }
    lgkm0();                                     // quadrant self-contained
    #pragma unroll
    for (int j = 0; j < 8; ++j) {                // coalesced 16B stores
      int row = j * 8 + (l >> 3), cc = l & 7;
      bf8 vv = *(const bf8*)(st + row * 68 + cc * 8);
      *(bf8*)(kT + (size_t)(mbase + row) * 256 + nbase + cc * 8) = vv;
    }
    #pragma unroll
    for (int mask = 1; mask <= 8; mask <<= 1)
      #pragma unroll
      for (int mt = 0; mt < 4; ++mt)
        #pragma unroll
        for (int r = 0; r < 4; ++r) rp[mt][r] += __shfl_xor(rp[mt][r], mask, 64);
    if (i == 0) {
      int pg = bn * 2 + wn;
      #pragma unroll
      for (int mt = 0; mt < 4; ++mt)
        #pragma unroll
        for (int r = 0; r < 4; ++r)
          s_part[pg * 32768 + mbase + mt * 16 + q * 4 + r] = rp[mt][r];
    }
  } else {                                       // v half -> vT permuted
    #pragma unroll
    for (int mt = 0; mt < 4; ++mt)
      #pragma unroll
      for (int nt = 0; nt < 4; ++nt) {
        int o2 = nbase + nt * 16 + i - 256;
        float bias = bv[o2];
        #pragma unroll
        for (int r = 0; r < 4; ++r) {
          float val = acc[mt][nt][r] + bias;
          int mg = mbase + mt * 16 + q * 4 + r;
          int b = mg >> 10, sp = mg & 1023;
          vT[((size_t)b * 256 + (sp & 255)) * 1024 + 4 * o2 + (sp >> 8)] = f2bf(val);
        }
      }
  }
}

// ---------------- K2 v2+fold: fused gram -> softmax -> PV -> OB ----------------
// Block = (64-row m-stripe bm, batch b), XCD-swizzled so each XCD owns 4
// batches. LDS: Apan 32K resident | Ppan 16K | Bst 32K = 2 bufs x 4 waves x
// 4KB. Counted vmcnt(4); 2 raw s_barriers per chunk. Row-sum combine
// (ex-K1b) folded into prologue via register sums. 2 blocks/CU.
__global__ __launch_bounds__(256, 2) void k2_fused(const short* __restrict__ kT,
                                                   const short* __restrict__ vT,
                                                   const float* __restrict__ s_part,
                                                   short* __restrict__ OB) {
  __shared__ __attribute__((aligned(16))) char smem[81920];
  char* Apan = smem;            // 32 KB: 4 k-panels x (64 rows x 128 B)
  char* Ppan = smem + 32768;    // 16 KB: 2 panels x (64 rows x 128 B)
  char* Bst  = smem + 49152;    // 32 KB: 2 bufs x 4 waves x 4 KB

  const int id = blockIdx.x;
  const int xcd = id & 7, slot = id >> 3;
  const int b  = xcd * 4 + (slot >> 4);   // 4 batches per XCD (L2-resident)
  const int bm = slot & 15;

  const int tid = threadIdx.x;
  const int w = tid >> 6, l = tid & 63;
  const int q = l >> 4, i = l & 15;
  const int srow = l >> 3;
  const int gcol = ((l & 7) ^ srow) * 8;

  const short* kTb = kT + (size_t)b * 1024 * 256;
  const short* vTb = vT + (size_t)b * 256 * 1024;

  char* slabA = Bst + w * 4096;            // even rounds
  char* slabB = Bst + 16384 + w * 4096;    // odd rounds

  const float sc1 = 1.0f / 16384.0f;             // (1/M)/16
  const float sc2 = 1.0f / 16777216.0f;          // (1/M^2)/16

  // ---- issue resident-A staging FIRST (latency hidden under fold) ----
  {
    const short* Am = kTb + (size_t)bm * 64 * 256;
    #pragma unroll
    for (int ks = 0; ks < 4; ++ks)
      #pragma unroll
      for (int j2 = 0; j2 < 2; ++j2) {
        int s2 = w * 2 + j2;
        gll16(Am + (size_t)(s2 * 8 + srow) * 256 + ks * 64 + gcol,
              Apan + ks * 8192 + s2 * 1024);
      }
  }

  // ---- row-sum combine (ex-K1b), register sums (R3-proven) ----
  const int mglob = b * 1024;
  float sm2[4][4];
  #pragma unroll
  for (int mt = 0; mt < 4; ++mt)
    #pragma unroll
    for (int r = 0; r < 4; ++r) {
      int m = mglob + bm * 64 + mt * 16 + q * 4 + r;
      sm2[mt][r] = (s_part[m] + s_part[32768 + m] + s_part[65536 + m] +
                    s_part[98304 + m]) * sc2;
    }
  float sn[8][2];
  #pragma unroll
  for (int c = 0; c < 8; ++c)
    #pragma unroll
    for (int nt = 0; nt < 2; ++nt) {
      int m = mglob + c * 128 + w * 32 + nt * 16 + i;
      sn[c][nt] = s_part[m] + s_part[32768 + m] + s_part[65536 + m] +
                  s_part[98304 + m];
    }

  // staging helpers: each wave stages exactly the rows its MFMAs read
  auto stageS = [&](int c, int ks, char* sl) {
    const short* Bn = kTb + (size_t)c * 128 * 256 + ks * 64 + gcol;
    #pragma unroll
    for (int j = 0; j < 4; ++j)
      gll16(Bn + (size_t)(w * 32 + j * 8 + srow) * 256, sl + j * 1024);
  };
  auto stageV = [&](int c, int ks2, int h, char* sl) {
    const short* Vn = vTb + c * 128 + ks2 * 64 + gcol;
    #pragma unroll
    for (int j = 0; j < 4; ++j)
      gll16(Vn + (size_t)(w * 64 + h * 32 + j * 8 + srow) * 1024, sl + j * 1024);
  };

  stageS(0, 0, slabA);                     // round 0
  stageS(0, 1, slabB);                     // round 1
  waitv<8>();                              // A landed; rounds 0/1 in flight
  barrier_relaxed();                       // A visible to all waves

  f32x4 zz = {0.f, 0.f, 0.f, 0.f};
  f32x4 acc_o[4][4];
  float rowsum[4][4];
  #pragma unroll
  for (int mt = 0; mt < 4; ++mt)
    #pragma unroll
    for (int ct = 0; ct < 4; ++ct) acc_o[mt][ct] = zz;
  #pragma unroll
  for (int mt = 0; mt < 4; ++mt)
    #pragma unroll
    for (int r = 0; r < 4; ++r) rowsum[mt][r] = 0.f;

  #pragma unroll
  for (int c = 0; c < 8; ++c) {
    f32x4 acc_s[4][2];
    #pragma unroll
    for (int mt = 0; mt < 4; ++mt)
      #pragma unroll
      for (int nt = 0; nt < 2; ++nt) acc_s[mt][nt] = zz;

    // ---- S rounds ks=0..3 (K=256): wait own vmcnt, compute, refill slab ----
    #pragma unroll
    for (int ks = 0; ks < 4; ++ks) {
      char* sl = (ks & 1) ? slabB : slabA;
      waitv<4>();                          // this round done; next in flight
      #pragma unroll
      for (int kq = 0; kq < 2; ++kq) {
        int sw = ((kq * 4 + q) ^ (i & 7)) * 16;
        bf8 af[4], bq2[2];
        #pragma unroll
        for (int mt = 0; mt < 4; ++mt)
          af[mt] = *(const bf8*)(Apan + ks * 8192 + (mt * 16 + i) * 128 + sw);
        #pragma unroll
        for (int nt = 0; nt < 2; ++nt)
          bq2[nt] = *(const bf8*)(sl + (nt * 16 + i) * 128 + sw);
        __builtin_amdgcn_s_setprio(1);
        #pragma unroll
        for (int mt = 0; mt < 4; ++mt)
          #pragma unroll
          for (int nt = 0; nt < 2; ++nt)
            acc_s[mt][nt] = MFMA16(af[mt], bq2[nt], acc_s[mt][nt]);
        __builtin_amdgcn_s_setprio(0);
      }
      lgkm0();                             // slab reads retired before refill
      if (ks < 2) stageS(c, ks + 2, sl);   // rounds 2,3: S ks+2
      else        stageV(c, 0, ks - 2, sl);// rounds 4,5: PV ks2=0, halves 0,1
    }

    // ---- exp -> P panels (PV rounds 4,5 in flight under this VALU work) ----
    barrier_relaxed();                     // prev chunk's P readers all done
    #pragma unroll
    for (int nt = 0; nt < 2; ++nt) {
      float snv = sn[c][nt];
      int nl = w * 32 + nt * 16 + i;
      char* pbase = Ppan + (nl >> 6) * 8192 + (nl & 7) * 2;
      int gchunk = (nl >> 3) & 7;
      #pragma unroll
      for (int mt = 0; mt < 4; ++mt)
        #pragma unroll
        for (int r = 0; r < 4; ++r) {
          int ml = mt * 16 + q * 4 + r;
          float p = __expf(acc_s[mt][nt][r] * sc1 - sm2[mt][r] * snv);
          rowsum[mt][r] += p;
          *(short*)(pbase + ml * 128 + ((gchunk ^ (ml & 7)) * 16)) = f2bf(p);
        }
    }
    lgkm0();                               // P writes complete
    barrier_relaxed();                     // P visible to all waves

    // ---- PV rounds (ks2,h) = (0,0),(0,1),(1,0),(1,1), K=128 ----
    #pragma unroll
    for (int pv = 0; pv < 4; ++pv) {
      char* sl = (pv & 1) ? slabB : slabA;
      const int ks2 = pv >> 1, h = pv & 1;
      if (c == 7 && pv == 3) waitv<0>(); else waitv<4>();
      #pragma unroll
      for (int kq = 0; kq < 2; ++kq) {
        int sw = ((kq * 4 + q) ^ (i & 7)) * 16;
        bf8 ap[4], bv2[2];
        #pragma unroll
        for (int mt = 0; mt < 4; ++mt)
          ap[mt] = *(const bf8*)(Ppan + ks2 * 8192 + (mt * 16 + i) * 128 + sw);
        #pragma unroll
        for (int u = 0; u < 2; ++u)
          bv2[u] = *(const bf8*)(sl + (u * 16 + i) * 128 + sw);
        __builtin_amdgcn_s_setprio(1);
        #pragma unroll
        for (int mt = 0; mt < 4; ++mt)
          #pragma unroll
          for (int u = 0; u < 2; ++u)
            acc_o[mt][h * 2 + u] = MFMA16(ap[mt], bv2[u], acc_o[mt][h * 2 + u]);
        __builtin_amdgcn_s_setprio(0);
      }
      lgkm0();
      if (pv < 2) stageV(c, 1, pv, sl);            // rounds 6,7: PV ks2=1
      else if (c < 7) stageS(c + 1, pv - 2, sl);   // next chunk S0,S1
    }
  }

  // ---- softmax rowsums: wave-reduce over i, block-reduce over waves ----
  #pragma unroll
  for (int mask = 1; mask <= 8; mask <<= 1)
    #pragma unroll
    for (int mt = 0; mt < 4; ++mt)
      #pragma unroll
      for (int r = 0; r < 4; ++r) rowsum[mt][r] += __shfl_xor(rowsum[mt][r], mask, 64);
  __syncthreads();                               // all PV P-reads done; reuse Ppan
  float* rs = (float*)Ppan;                      // [4 waves][64 m]
  if (i == 0) {
    #pragma unroll
    for (int mt = 0; mt < 4; ++mt)
      #pragma unroll
      for (int r = 0; r < 4; ++r)
        rs[w * 64 + mt * 16 + q * 4 + r] = rowsum[mt][r];
  }
  __syncthreads();
  float rinv[4][4];
  #pragma unroll
  for (int mt = 0; mt < 4; ++mt)
    #pragma unroll
    for (int r = 0; r < 4; ++r) {
      int m = mt * 16 + q * 4 + r;
      rinv[mt][r] = 1.0f / (rs[m] + rs[64 + m] + rs[128 + m] + rs[192 + m]);
    }
  // ---- normalize + OB write via per-wave LDS restage (self-contained slot) ----
  short* ob = (short*)(Bst + w * 8192);          // 256 rows x 16 shorts
  #pragma unroll
  for (int mt = 0; mt < 4; ++mt)
    #pragma unroll
    for (int ct = 0; ct < 4; ++ct)
      #pragma unroll
      for (int r = 0; r < 4; ++r)
        ob[(r * 64 + ct * 16 + i) * 16 + mt * 4 + q] =
            f2bf(acc_o[mt][ct][r] * rinv[mt][r]);
  short* obg = OB + (size_t)b * 1024 * 256;
  #pragma unroll
  for (int jj = 0; jj < 8; ++jj) {
    int lr = jj * 32 + (l >> 1), ch = l & 1;
    bf8 vv = *(const bf8*)(ob + lr * 16 + ch * 8);
    int rr = lr >> 6, cc = lr & 63;
    *(bf8*)(obg + ((size_t)(rr * 256 + w * 64 + cc)) * 256 + bm * 16 + ch * 8) = vv;
  }
}

// ---------------- K3: output projection + bias + residual ----------------
__global__ __launch_bounds__(256, 2) void k3_out(const short* __restrict__ Wo_bf,
                                                 const short* __restrict__ OB,
                                                 const float* __restrict__ bo,
                                                 const float* __restrict__ x,
                                                 float* __restrict__ out) {
  __shared__ __attribute__((aligned(16))) char smem[36864];
  f32x4 acc[4][4];
  int bm = blockIdx.x, bn = blockIdx.y, b = blockIdx.z;
  gemm_core(Wo_bf + (size_t)bm * 128 * 256,
            OB + ((size_t)b * 1024 + bn * 128) * 256, 256, 256, 4, smem, acc);
  int tid = threadIdx.x;
  int w = tid >> 6, l = tid & 63, q = l >> 4, i = l & 15;
  int wm = w & 1, wn = w >> 1;
  int oloc = bm * 128 + wm * 64, sploc = bn * 128 + wn * 64;
  __syncthreads();                               // gemm tile reads done
  // per-wave LDS quadrant: 32 rows x 66 f32 (padded), 8448 B each; 2 halves
  float* st = (float*)smem + w * 2112;
  #pragma unroll
  for (int half = 0; half < 2; ++half) {
    if (half) lgkm0();                           // half-0 reads retired
    #pragma unroll
    for (int mtl = 0; mtl < 2; ++mtl) {
      int mt = half * 2 + mtl;
      #pragma unroll
      for (int nt = 0; nt < 4; ++nt)
        #pragma unroll
        for (int r = 0; r < 4; ++r)
          st[(mtl * 16 + q * 4 + r) * 66 + nt * 16 + i] = acc[mt][nt][r];
    }
    lgkm0();                                     // quadrant self-contained
    #pragma unroll
    for (int j = 0; j < 8; ++j) {
      int row = j * 4 + (l >> 4), c4 = l & 15;
      f32x4 v = *(const f32x4*)(st + row * 66 + c4 * 4);
      int o = oloc + half * 32 + row;
      int sp = sploc + c4 * 4;
      size_t idx = ((size_t)b * 512 + o) * 1024 + sp;
      float4 xv = *(const float4*)(x + idx);
      float bias = bo[o];
      float4 ov;
      ov.x = v[0] + bias + xv.x;
      ov.y = v[1] + bias + xv.y;
      ov.z = v[2] + bias + xv.z;
      ov.w = v[3] + bias + xv.w;
      *(float4*)(out + idx) = ov;
    }
  }
}

extern "C" void kernel_launch(void* const* d_in, const int* in_sizes, int n_in,
                              void* d_out, int out_size, void* d_ws, size_t ws_size,
                              hipStream_t stream) {
  (void)in_sizes; (void)n_in; (void)out_size; (void)ws_size;
  const float* x  = (const float*)d_in[0];
  const float* Wk = (const float*)d_in[1];
  const float* bk = (const float*)d_in[2];
  const float* Wv = (const float*)d_in[3];
  const float* bv = (const float*)d_in[4];
  const float* Wo = (const float*)d_in[5];
  const float* bo = (const float*)d_in[6];
  float* out = (float*)d_out;
  char* ws = (char*)d_ws;

  // ws layout (~68.5 MB), time-aliased:
  //   [0,32M)   : xT (P0->K1, 32 MB) then OB (K2->K3, 16 MB)
  //   [32M,48M) : kT (K1->K2)
  //   [48M,64M) : vT (K1->K2)
  //   [64M,...) : weights + reduction buffers
  short* xT     = (short*)(ws);
  short* OB     = (short*)(ws);
  short* kTb    = (short*)(ws + 33554432);
  short* vTb    = (short*)(ws + 50331648);
  short* Wkv_bf = (short*)(ws + 67108864);
  short* Wo_bf  = (short*)(ws + 67633152);
  float* s_part = (float*)(ws + 67895296);

  p0_xpose<<<dim3(8, 16, 32), 256, 0, stream>>>(x, xT);
  w0_weights<<<1536, 256, 0, stream>>>(Wk, Wv, Wo, Wkv_bf, Wo_bf);
  k1_kv<<<dim3(256, 4), 256, 0, stream>>>(xT, Wkv_bf, bk, bv, kTb, vTb, s_part);
  k2_fused<<<dim3(512), 256, 0, stream>>>(kTb, vTb, s_part, OB);
  k3_out<<<dim3(4, 8, 32), 256, 0, stream>>>(Wo_bf, OB, bo, x, out);
}

// Round 6
// 222.535 us; speedup vs baseline: 1.4990x; 1.0649x over previous
//
#include <hip/hip_runtime.h>

// B=32, C=512, c2=256, M=1024. All GEMMs bf16 MFMA (fp32 accum), m97-style:
// 128x128 (or fused) tiles, BK=64, global_load_lds(16B) staging, XOR-swizzled
// chunks.
//
// P0 : x[b][c][sp] fp32 -> xT[b*1024+sp][c] bf16, FUSED with weight casts
//      (blocks >= 4096 do Wkv/Wo bf16 cast) -- one launch fewer
// K1 : [32768x512]x[512x512], 1D grid XCD-swizzled: each XCD owns a
//      contiguous bm-range (4MB of xT = one L2), bn fastest -> A-tile
//      L2-resident, ~96MB HBM refetch removed. k-half -> kT + row-sum
//      partials (LDS-restaged 16B stores), v-half -> vT permuted scatter.
// K2 : FUSED flash-style attention per (64-row m-stripe, batch) -- R1-proven
//      v2 pipeline + K1b fold (unchanged from R5, control).
// K3 : out = Wo @ O2 + bo + x, 1D grid: each XCD owns 4 batches, bm fastest
//      (consecutive blocks share the OB B-tile). float4 epilogue.

typedef short bf8 __attribute__((ext_vector_type(8)));
typedef float f32x4 __attribute__((ext_vector_type(4)));

#define MFMA16(a, b, c) __builtin_amdgcn_mfma_f32_16x16x32_bf16((a), (b), (c), 0, 0, 0)

__device__ __forceinline__ short f2bf(float x) {
  unsigned u = __float_as_uint(x);
  u += 0x7fffu + ((u >> 16) & 1u);   // RNE, finite inputs
  return (short)(u >> 16);
}

__device__ __forceinline__ void gll16(const short* g, void* l) {
  __builtin_amdgcn_global_load_lds(
      (const __attribute__((address_space(1))) unsigned int*)g,
      (__attribute__((address_space(3))) unsigned int*)l, 16, 0, 0);
}

__device__ __forceinline__ void lgkm0() {
  asm volatile("s_waitcnt lgkmcnt(0)" ::: "memory");
}
template <int N>
__device__ __forceinline__ void waitv() {
  static_assert(N == 0 || N == 4 || N == 8, "bad vmcnt");
  if constexpr (N == 0) asm volatile("s_waitcnt vmcnt(0)" ::: "memory");
  else if constexpr (N == 4) asm volatile("s_waitcnt vmcnt(4)" ::: "memory");
  else asm volatile("s_waitcnt vmcnt(8)" ::: "memory");
}
__device__ __forceinline__ void barrier_relaxed() {
  asm volatile("" ::: "memory");
  __builtin_amdgcn_s_barrier();
  asm volatile("" ::: "memory");
}

// ---- shared GEMM core (R1-proven): C[128][128] tile, single 32KB buffer ----
__device__ __forceinline__ void gemm_core(const short* __restrict__ A,
                                          const short* __restrict__ B,
                                          int ldA, int ldB, int ksteps,
                                          char* smem, f32x4 acc[4][4]) {
  const int tid = threadIdx.x;
  const int w = tid >> 6, l = tid & 63;
  const int q = l >> 4, i = l & 15;
  const int wm = w & 1, wn = w >> 1;
  const int srow = l >> 3;
  const int gcol = ((l & 7) ^ srow) * 8;        // swizzled 16B chunk (shorts)
  f32x4 zz = {0.f, 0.f, 0.f, 0.f};
  #pragma unroll
  for (int mt = 0; mt < 4; ++mt)
    #pragma unroll
    for (int nt = 0; nt < 4; ++nt) acc[mt][nt] = zz;

  for (int ks = 0; ks < ksteps; ++ks) {
    __syncthreads();                            // LDS free (prev reads done)
    const short* Ak = A + ks * 64 + gcol;
    const short* Bk = B + ks * 64 + gcol;
    #pragma unroll
    for (int j = 0; j < 4; ++j) {
      int s = w * 4 + j;
      size_t row = (size_t)(s * 8 + srow);
      gll16(Ak + row * ldA, smem + s * 1024);
      gll16(Bk + row * ldB, smem + 16384 + s * 1024);
    }
    __syncthreads();                            // staged data visible
    #pragma unroll
    for (int kq = 0; kq < 2; ++kq) {
      int sw = ((kq * 4 + q) ^ (i & 7)) * 16;   // swizzled read offset (bytes)
      bf8 af[4], bq[4];
      #pragma unroll
      for (int mt = 0; mt < 4; ++mt)
        af[mt] = *(const bf8*)(smem + (wm * 64 + mt * 16 + i) * 128 + sw);
      #pragma unroll
      for (int nt = 0; nt < 4; ++nt)
        bq[nt] = *(const bf8*)(smem + 16384 + (wn * 64 + nt * 16 + i) * 128 + sw);
      #pragma unroll
      for (int mt = 0; mt < 4; ++mt)
        #pragma unroll
        for (int nt = 0; nt < 4; ++nt)
          acc[mt][nt] = MFMA16(af[mt], bq[nt], acc[mt][nt]);
    }
  }
}

// ---------------- P0: transpose + convert x, fused weight casts ----------------
__global__ __launch_bounds__(256) void p0_fused(const float* __restrict__ x,
                                                short* __restrict__ xT,
                                                const float* __restrict__ Wk,
                                                const float* __restrict__ Wv,
                                                const float* __restrict__ Wo,
                                                short* __restrict__ Wkv_bf,
                                                short* __restrict__ Wo_bf) {
  __shared__ float lds[64][65];
  int id = blockIdx.x;
  int t = threadIdx.x;
  if (id >= 4096) {                              // weight-cast blocks
    int g = (id - 4096) * 256 + t;
    if (g < 262144) {
      int o = g >> 9, c = g & 511;
      float v = (o < 256) ? Wk[o * 512 + c] : Wv[(o - 256) * 512 + c];
      Wkv_bf[g] = f2bf(v);
    } else {
      int i2 = g - 262144;
      Wo_bf[i2] = f2bf(Wo[i2]);
    }
    return;
  }
  int cb = id & 7, sb = (id >> 3) & 15, b = id >> 7;
  int c0 = cb * 64, sp0 = sb * 64;
  const float4* x4 = reinterpret_cast<const float4*>(x);
  #pragma unroll
  for (int j = 0; j < 4; ++j) {
    int lin = t + 256 * j;
    int cl = lin >> 4, s4 = lin & 15;
    float4 v = x4[(((size_t)b * 512 + c0 + cl) * 1024 + sp0 + s4 * 4) >> 2];
    lds[cl][s4 * 4 + 0] = v.x; lds[cl][s4 * 4 + 1] = v.y;
    lds[cl][s4 * 4 + 2] = v.z; lds[cl][s4 * 4 + 3] = v.w;
  }
  __syncthreads();
  int spl = t >> 2, cs = (t & 3) * 16;
  bf8 o0, o1;
  #pragma unroll
  for (int j = 0; j < 8; ++j) o0[j] = f2bf(lds[cs + j][spl]);
  #pragma unroll
  for (int j = 0; j < 8; ++j) o1[j] = f2bf(lds[cs + 8 + j][spl]);
  size_t base = ((size_t)b * 1024 + sp0 + spl) * 512 + c0 + cs;
  *reinterpret_cast<bf8*>(xT + base) = o0;
  *reinterpret_cast<bf8*>(xT + base + 8) = o1;
}

// ---------------- K1: fused k/v projection GEMM (XCD-swizzled) ----------------
__global__ __launch_bounds__(256, 2) void k1_kv(const short* __restrict__ xT,
                                                const short* __restrict__ Wkv,
                                                const float* __restrict__ bk,
                                                const float* __restrict__ bv,
                                                short* __restrict__ kT,
                                                short* __restrict__ vT,
                                                float* __restrict__ s_part) {
  __shared__ __attribute__((aligned(16))) char smem[36864];
  f32x4 acc[4][4];
  // XCD-swizzle: each XCD owns contiguous bm-range (4MB xT, L2-resident);
  // bn fastest so 4 consecutive blocks share the A-tile.
  int id = blockIdx.x;
  int xcd = id & 7, slot = id >> 3;              // 128 slots per XCD
  int bm = xcd * 32 + (slot >> 2);
  int bn = slot & 3;
  gemm_core(xT + (size_t)bm * 128 * 512, Wkv + (size_t)bn * 128 * 512,
            512, 512, 8, smem, acc);
  int tid = threadIdx.x;
  int w = tid >> 6, l = tid & 63, q = l >> 4, i = l & 15;
  int wm = w & 1, wn = w >> 1;
  int mbase = bm * 128 + wm * 64;
  int nbase = bn * 128 + wn * 64;
  if (bn < 2) {                                  // k half
    __syncthreads();                             // gemm tile reads done
    // per-wave LDS quadrant: 64 rows x 68 shorts (padded), 8704 B each
    short* st = (short*)smem + w * 4352;
    float rp[4][4];
    #pragma unroll
    for (int mt = 0; mt < 4; ++mt)
      #pragma unroll
      for (int r = 0; r < 4; ++r) rp[mt][r] = 0.f;
    #pragma unroll
    for (int mt = 0; mt < 4; ++mt)
      #pragma unroll
      for (int nt = 0; nt < 4; ++nt) {
        float bias = bk[nbase + nt * 16 + i];
        #pragma unroll
        for (int r = 0; r < 4; ++r) {
          float val = acc[mt][nt][r] + bias;
          st[(mt * 16 + q * 4 + r) * 68 + nt * 16 + i] = f2bf(val);
          rp[mt][r] += val;
        }
      }
    lgkm0();                                     // quadrant self-contained
    #pragma unroll
    for (int j = 0; j < 8; ++j) {                // coalesced 16B stores
      int row = j * 8 + (l >> 3), cc = l & 7;
      bf8 vv = *(const bf8*)(st + row * 68 + cc * 8);
      *(bf8*)(kT + (size_t)(mbase + row) * 256 + nbase + cc * 8) = vv;
    }
    #pragma unroll
    for (int mask = 1; mask <= 8; mask <<= 1)
      #pragma unroll
      for (int mt = 0; mt < 4; ++mt)
        #pragma unroll
        for (int r = 0; r < 4; ++r) rp[mt][r] += __shfl_xor(rp[mt][r], mask, 64);
    if (i == 0) {
      int pg = bn * 2 + wn;
      #pragma unroll
      for (int mt = 0; mt < 4; ++mt)
        #pragma unroll
        for (int r = 0; r < 4; ++r)
          s_part[pg * 32768 + mbase + mt * 16 + q * 4 + r] = rp[mt][r];
    }
  } else {                                       // v half -> vT permuted
    #pragma unroll
    for (int mt = 0; mt < 4; ++mt)
      #pragma unroll
      for (int nt = 0; nt < 4; ++nt) {
        int o2 = nbase + nt * 16 + i - 256;
        float bias = bv[o2];
        #pragma unroll
        for (int r = 0; r < 4; ++r) {
          float val = acc[mt][nt][r] + bias;
          int mg = mbase + mt * 16 + q * 4 + r;
          int b = mg >> 10, sp = mg & 1023;
          vT[((size_t)b * 256 + (sp & 255)) * 1024 + 4 * o2 + (sp >> 8)] = f2bf(val);
        }
      }
  }
}

// ---------------- K2 v2+fold: fused gram -> softmax -> PV -> OB ----------------
// (unchanged from R5 -- control at ~53.4us)
__global__ __launch_bounds__(256, 2) void k2_fused(const short* __restrict__ kT,
                                                   const short* __restrict__ vT,
                                                   const float* __restrict__ s_part,
                                                   short* __restrict__ OB) {
  __shared__ __attribute__((aligned(16))) char smem[81920];
  char* Apan = smem;            // 32 KB: 4 k-panels x (64 rows x 128 B)
  char* Ppan = smem + 32768;    // 16 KB: 2 panels x (64 rows x 128 B)
  char* Bst  = smem + 49152;    // 32 KB: 2 bufs x 4 waves x 4 KB

  const int id = blockIdx.x;
  const int xcd = id & 7, slot = id >> 3;
  const int b  = xcd * 4 + (slot >> 4);   // 4 batches per XCD (L2-resident)
  const int bm = slot & 15;

  const int tid = threadIdx.x;
  const int w = tid >> 6, l = tid & 63;
  const int q = l >> 4, i = l & 15;
  const int srow = l >> 3;
  const int gcol = ((l & 7) ^ srow) * 8;

  const short* kTb = kT + (size_t)b * 1024 * 256;
  const short* vTb = vT + (size_t)b * 256 * 1024;

  char* slabA = Bst + w * 4096;            // even rounds
  char* slabB = Bst + 16384 + w * 4096;    // odd rounds

  const float sc1 = 1.0f / 16384.0f;             // (1/M)/16
  const float sc2 = 1.0f / 16777216.0f;          // (1/M^2)/16

  // ---- issue resident-A staging FIRST (latency hidden under fold) ----
  {
    const short* Am = kTb + (size_t)bm * 64 * 256;
    #pragma unroll
    for (int ks = 0; ks < 4; ++ks)
      #pragma unroll
      for (int j2 = 0; j2 < 2; ++j2) {
        int s2 = w * 2 + j2;
        gll16(Am + (size_t)(s2 * 8 + srow) * 256 + ks * 64 + gcol,
              Apan + ks * 8192 + s2 * 1024);
      }
  }

  // ---- row-sum combine (ex-K1b), register sums ----
  const int mglob = b * 1024;
  float sm2[4][4];
  #pragma unroll
  for (int mt = 0; mt < 4; ++mt)
    #pragma unroll
    for (int r = 0; r < 4; ++r) {
      int m = mglob + bm * 64 + mt * 16 + q * 4 + r;
      sm2[mt][r] = (s_part[m] + s_part[32768 + m] + s_part[65536 + m] +
                    s_part[98304 + m]) * sc2;
    }
  float sn[8][2];
  #pragma unroll
  for (int c = 0; c < 8; ++c)
    #pragma unroll
    for (int nt = 0; nt < 2; ++nt) {
      int m = mglob + c * 128 + w * 32 + nt * 16 + i;
      sn[c][nt] = s_part[m] + s_part[32768 + m] + s_part[65536 + m] +
                  s_part[98304 + m];
    }

  // staging helpers: each wave stages exactly the rows its MFMAs read
  auto stageS = [&](int c, int ks, char* sl) {
    const short* Bn = kTb + (size_t)c * 128 * 256 + ks * 64 + gcol;
    #pragma unroll
    for (int j = 0; j < 4; ++j)
      gll16(Bn + (size_t)(w * 32 + j * 8 + srow) * 256, sl + j * 1024);
  };
  auto stageV = [&](int c, int ks2, int h, char* sl) {
    const short* Vn = vTb + c * 128 + ks2 * 64 + gcol;
    #pragma unroll
    for (int j = 0; j < 4; ++j)
      gll16(Vn + (size_t)(w * 64 + h * 32 + j * 8 + srow) * 1024, sl + j * 1024);
  };

  stageS(0, 0, slabA);                     // round 0
  stageS(0, 1, slabB);                     // round 1
  waitv<8>();                              // A landed; rounds 0/1 in flight
  barrier_relaxed();                       // A visible to all waves

  f32x4 zz = {0.f, 0.f, 0.f, 0.f};
  f32x4 acc_o[4][4];
  float rowsum[4][4];
  #pragma unroll
  for (int mt = 0; mt < 4; ++mt)
    #pragma unroll
    for (int ct = 0; ct < 4; ++ct) acc_o[mt][ct] = zz;
  #pragma unroll
  for (int mt = 0; mt < 4; ++mt)
    #pragma unroll
    for (int r = 0; r < 4; ++r) rowsum[mt][r] = 0.f;

  #pragma unroll
  for (int c = 0; c < 8; ++c) {
    f32x4 acc_s[4][2];
    #pragma unroll
    for (int mt = 0; mt < 4; ++mt)
      #pragma unroll
      for (int nt = 0; nt < 2; ++nt) acc_s[mt][nt] = zz;

    // ---- S rounds ks=0..3 (K=256): wait own vmcnt, compute, refill slab ----
    #pragma unroll
    for (int ks = 0; ks < 4; ++ks) {
      char* sl = (ks & 1) ? slabB : slabA;
      waitv<4>();                          // this round done; next in flight
      #pragma unroll
      for (int kq = 0; kq < 2; ++kq) {
        int sw = ((kq * 4 + q) ^ (i & 7)) * 16;
        bf8 af[4], bq2[2];
        #pragma unroll
        for (int mt = 0; mt < 4; ++mt)
          af[mt] = *(const bf8*)(Apan + ks * 8192 + (mt * 16 + i) * 128 + sw);
        #pragma unroll
        for (int nt = 0; nt < 2; ++nt)
          bq2[nt] = *(const bf8*)(sl + (nt * 16 + i) * 128 + sw);
        __builtin_amdgcn_s_setprio(1);
        #pragma unroll
        for (int mt = 0; mt < 4; ++mt)
          #pragma unroll
          for (int nt = 0; nt < 2; ++nt)
            acc_s[mt][nt] = MFMA16(af[mt], bq2[nt], acc_s[mt][nt]);
        __builtin_amdgcn_s_setprio(0);
      }
      lgkm0();                             // slab reads retired before refill
      if (ks < 2) stageS(c, ks + 2, sl);   // rounds 2,3: S ks+2
      else        stageV(c, 0, ks - 2, sl);// rounds 4,5: PV ks2=0, halves 0,1
    }

    // ---- exp -> P panels (PV rounds 4,5 in flight under this VALU work) ----
    barrier_relaxed();                     // prev chunk's P readers all done
    #pragma unroll
    for (int nt = 0; nt < 2; ++nt) {
      float snv = sn[c][nt];
      int nl = w * 32 + nt * 16 + i;
      char* pbase = Ppan + (nl >> 6) * 8192 + (nl & 7) * 2;
      int gchunk = (nl >> 3) & 7;
      #pragma unroll
      for (int mt = 0; mt < 4; ++mt)
        #pragma unroll
        for (int r = 0; r < 4; ++r) {
          int ml = mt * 16 + q * 4 + r;
          float p = __expf(acc_s[mt][nt][r] * sc1 - sm2[mt][r] * snv);
          rowsum[mt][r] += p;
          *(short*)(pbase + ml * 128 + ((gchunk ^ (ml & 7)) * 16)) = f2bf(p);
        }
    }
    lgkm0();                               // P writes complete
    barrier_relaxed();                     // P visible to all waves

    // ---- PV rounds (ks2,h) = (0,0),(0,1),(1,0),(1,1), K=128 ----
    #pragma unroll
    for (int pv = 0; pv < 4; ++pv) {
      char* sl = (pv & 1) ? slabB : slabA;
      const int ks2 = pv >> 1, h = pv & 1;
      if (c == 7 && pv == 3) waitv<0>(); else waitv<4>();
      #pragma unroll
      for (int kq = 0; kq < 2; ++kq) {
        int sw = ((kq * 4 + q) ^ (i & 7)) * 16;
        bf8 ap[4], bv2[2];
        #pragma unroll
        for (int mt = 0; mt < 4; ++mt)
          ap[mt] = *(const bf8*)(Ppan + ks2 * 8192 + (mt * 16 + i) * 128 + sw);
        #pragma unroll
        for (int u = 0; u < 2; ++u)
          bv2[u] = *(const bf8*)(sl + (u * 16 + i) * 128 + sw);
        __builtin_amdgcn_s_setprio(1);
        #pragma unroll
        for (int mt = 0; mt < 4; ++mt)
          #pragma unroll
          for (int u = 0; u < 2; ++u)
            acc_o[mt][h * 2 + u] = MFMA16(ap[mt], bv2[u], acc_o[mt][h * 2 + u]);
        __builtin_amdgcn_s_setprio(0);
      }
      lgkm0();
      if (pv < 2) stageV(c, 1, pv, sl);            // rounds 6,7: PV ks2=1
      else if (c < 7) stageS(c + 1, pv - 2, sl);   // next chunk S0,S1
    }
  }

  // ---- softmax rowsums: wave-reduce over i, block-reduce over waves ----
  #pragma unroll
  for (int mask = 1; mask <= 8; mask <<= 1)
    #pragma unroll
    for (int mt = 0; mt < 4; ++mt)
      #pragma unroll
      for (int r = 0; r < 4; ++r) rowsum[mt][r] += __shfl_xor(rowsum[mt][r], mask, 64);
  __syncthreads();                               // all PV P-reads done; reuse Ppan
  float* rs = (float*)Ppan;                      // [4 waves][64 m]
  if (i == 0) {
    #pragma unroll
    for (int mt = 0; mt < 4; ++mt)
      #pragma unroll
      for (int r = 0; r < 4; ++r)
        rs[w * 64 + mt * 16 + q * 4 + r] = rowsum[mt][r];
  }
  __syncthreads();
  float rinv[4][4];
  #pragma unroll
  for (int mt = 0; mt < 4; ++mt)
    #pragma unroll
    for (int r = 0; r < 4; ++r) {
      int m = mt * 16 + q * 4 + r;
      rinv[mt][r] = 1.0f / (rs[m] + rs[64 + m] + rs[128 + m] + rs[192 + m]);
    }
  // ---- normalize + OB write via per-wave LDS restage (self-contained slot) ----
  short* ob = (short*)(Bst + w * 8192);          // 256 rows x 16 shorts
  #pragma unroll
  for (int mt = 0; mt < 4; ++mt)
    #pragma unroll
    for (int ct = 0; ct < 4; ++ct)
      #pragma unroll
      for (int r = 0; r < 4; ++r)
        ob[(r * 64 + ct * 16 + i) * 16 + mt * 4 + q] =
            f2bf(acc_o[mt][ct][r] * rinv[mt][r]);
  short* obg = OB + (size_t)b * 1024 * 256;
  #pragma unroll
  for (int jj = 0; jj < 8; ++jj) {
    int lr = jj * 32 + (l >> 1), ch = l & 1;
    bf8 vv = *(const bf8*)(ob + lr * 16 + ch * 8);
    int rr = lr >> 6, cc = lr & 63;
    *(bf8*)(obg + ((size_t)(rr * 256 + w * 64 + cc)) * 256 + bm * 16 + ch * 8) = vv;
  }
}

// ---------------- K3: output projection + bias + residual (XCD-swizzled) ----------------
__global__ __launch_bounds__(256, 2) void k3_out(const short* __restrict__ Wo_bf,
                                                 const short* __restrict__ OB,
                                                 const float* __restrict__ bo,
                                                 const float* __restrict__ x,
                                                 float* __restrict__ out) {
  __shared__ __attribute__((aligned(16))) char smem[36864];
  f32x4 acc[4][4];
  // XCD-swizzle: each XCD owns 4 batches; bm fastest so 4 consecutive
  // blocks share the OB B-tile.
  int id = blockIdx.x;
  int xcd = id & 7, slot = id >> 3;              // 128 slots per XCD
  int b = xcd * 4 + (slot >> 5);
  int rem = slot & 31;
  int bn = rem >> 2, bm = rem & 3;
  gemm_core(Wo_bf + (size_t)bm * 128 * 256,
            OB + ((size_t)b * 1024 + bn * 128) * 256, 256, 256, 4, smem, acc);
  int tid = threadIdx.x;
  int w = tid >> 6, l = tid & 63, q = l >> 4, i = l & 15;
  int wm = w & 1, wn = w >> 1;
  int oloc = bm * 128 + wm * 64, sploc = bn * 128 + wn * 64;
  __syncthreads();                               // gemm tile reads done
  // per-wave LDS quadrant: 32 rows x 66 f32 (padded), 8448 B each; 2 halves
  float* st = (float*)smem + w * 2112;
  #pragma unroll
  for (int half = 0; half < 2; ++half) {
    if (half) lgkm0();                           // half-0 reads retired
    #pragma unroll
    for (int mtl = 0; mtl < 2; ++mtl) {
      int mt = half * 2 + mtl;
      #pragma unroll
      for (int nt = 0; nt < 4; ++nt)
        #pragma unroll
        for (int r = 0; r < 4; ++r)
          st[(mtl * 16 + q * 4 + r) * 66 + nt * 16 + i] = acc[mt][nt][r];
    }
    lgkm0();                                     // quadrant self-contained
    #pragma unroll
    for (int j = 0; j < 8; ++j) {
      int row = j * 4 + (l >> 4), c4 = l & 15;
      f32x4 v = *(const f32x4*)(st + row * 66 + c4 * 4);
      int o = oloc + half * 32 + row;
      int sp = sploc + c4 * 4;
      size_t idx = ((size_t)b * 512 + o) * 1024 + sp;
      float4 xv = *(const float4*)(x + idx);
      float bias = bo[o];
      float4 ov;
      ov.x = v[0] + bias + xv.x;
      ov.y = v[1] + bias + xv.y;
      ov.z = v[2] + bias + xv.z;
      ov.w = v[3] + bias + xv.w;
      *(float4*)(out + idx) = ov;
    }
  }
}

extern "C" void kernel_launch(void* const* d_in, const int* in_sizes, int n_in,
                              void* d_out, int out_size, void* d_ws, size_t ws_size,
                              hipStream_t stream) {
  (void)in_sizes; (void)n_in; (void)out_size; (void)ws_size;
  const float* x  = (const float*)d_in[0];
  const float* Wk = (const float*)d_in[1];
  const float* bk = (const float*)d_in[2];
  const float* Wv = (const float*)d_in[3];
  const float* bv = (const float*)d_in[4];
  const float* Wo = (const float*)d_in[5];
  const float* bo = (const float*)d_in[6];
  float* out = (float*)d_out;
  char* ws = (char*)d_ws;

  // ws layout (~68.5 MB), time-aliased:
  //   [0,32M)   : xT (P0->K1, 32 MB) then OB (K2->K3, 16 MB)
  //   [32M,48M) : kT (K1->K2)
  //   [48M,64M) : vT (K1->K2)
  //   [64M,...) : weights + reduction buffers
  short* xT     = (short*)(ws);
  short* OB     = (short*)(ws);
  short* kTb    = (short*)(ws + 33554432);
  short* vTb    = (short*)(ws + 50331648);
  short* Wkv_bf = (short*)(ws + 67108864);
  short* Wo_bf  = (short*)(ws + 67633152);
  float* s_part = (float*)(ws + 67895296);

  p0_fused<<<5632, 256, 0, stream>>>(x, xT, Wk, Wv, Wo, Wkv_bf, Wo_bf);
  k1_kv<<<1024, 256, 0, stream>>>(xT, Wkv_bf, bk, bv, kTb, vTb, s_part);
  k2_fused<<<512, 256, 0, stream>>>(kTb, vTb, s_part, OB);
  k3_out<<<1024, 256, 0, stream>>>(Wo_bf, OB, bo, x, out);
}

// Round 7
// 221.708 us; speedup vs baseline: 1.5046x; 1.0037x over previous
//
#include <hip/hip_runtime.h>

// B=32, C=512, c2=256, M=1024. All GEMMs bf16 MFMA (fp32 accum), m97-style:
// 128x128 (or fused) tiles, BK=64, global_load_lds(16B) staging, XOR-swizzled
// chunks.
//
// P0 : x[b][c][sp] fp32 -> xT[b*1024+sp][c] bf16, FUSED with weight casts
// K1 : [32768x512]x[512x512], XCD-swizzled. k-half (bn 0,1): kT + row-sum
//      partials, LDS-restaged 16B stores. v-half (bn 2,3): A-rows PERMUTED
//      (hi-group x 32-sp chunk) so the vT reshape-scatter becomes 256
//      consecutive columns -> LDS-restaged coalesced 16B stores (was 64
//      scalar 2B stores/thread = 8.4M insts).
// K2 : FUSED flash-style attention (R6-identical control, ~54us).
// K3 : out = Wo @ O2 + bo + x (R6-identical).

typedef short bf8 __attribute__((ext_vector_type(8)));
typedef float f32x4 __attribute__((ext_vector_type(4)));

#define MFMA16(a, b, c) __builtin_amdgcn_mfma_f32_16x16x32_bf16((a), (b), (c), 0, 0, 0)

__device__ __forceinline__ short f2bf(float x) {
  unsigned u = __float_as_uint(x);
  u += 0x7fffu + ((u >> 16) & 1u);   // RNE, finite inputs
  return (short)(u >> 16);
}

__device__ __forceinline__ void gll16(const short* g, void* l) {
  __builtin_amdgcn_global_load_lds(
      (const __attribute__((address_space(1))) unsigned int*)g,
      (__attribute__((address_space(3))) unsigned int*)l, 16, 0, 0);
}

__device__ __forceinline__ void lgkm0() {
  asm volatile("s_waitcnt lgkmcnt(0)" ::: "memory");
}
template <int N>
__device__ __forceinline__ void waitv() {
  static_assert(N == 0 || N == 4 || N == 8, "bad vmcnt");
  if constexpr (N == 0) asm volatile("s_waitcnt vmcnt(0)" ::: "memory");
  else if constexpr (N == 4) asm volatile("s_waitcnt vmcnt(4)" ::: "memory");
  else asm volatile("s_waitcnt vmcnt(8)" ::: "memory");
}
__device__ __forceinline__ void barrier_relaxed() {
  asm volatile("" ::: "memory");
  __builtin_amdgcn_s_barrier();
  asm volatile("" ::: "memory");
}

// ---- shared GEMM core (R1-proven): C[128][128] tile, single 32KB buffer.
// VPERM: A-tile rows permuted as row_g = (rho>>5)*256 + (rho&31) relative to
// base (wave w = hi-group w); B staging and fragment reads unchanged.
template <bool VPERM>
__device__ __forceinline__ void gemm_core(const short* __restrict__ A,
                                          const short* __restrict__ B,
                                          int ldA, int ldB, int ksteps,
                                          char* smem, f32x4 acc[4][4]) {
  const int tid = threadIdx.x;
  const int w = tid >> 6, l = tid & 63;
  const int q = l >> 4, i = l & 15;
  const int wm = w & 1, wn = w >> 1;
  const int srow = l >> 3;
  const int gcol = ((l & 7) ^ srow) * 8;        // swizzled 16B chunk (shorts)
  f32x4 zz = {0.f, 0.f, 0.f, 0.f};
  #pragma unroll
  for (int mt = 0; mt < 4; ++mt)
    #pragma unroll
    for (int nt = 0; nt < 4; ++nt) acc[mt][nt] = zz;

  for (int ks = 0; ks < ksteps; ++ks) {
    __syncthreads();                            // LDS free (prev reads done)
    const short* Ak = A + ks * 64 + gcol;
    const short* Bk = B + ks * 64 + gcol;
    #pragma unroll
    for (int j = 0; j < 4; ++j) {
      int s = w * 4 + j;
      size_t arow = VPERM ? (size_t)(w * 256 + j * 8 + srow)
                          : (size_t)(s * 8 + srow);
      gll16(Ak + arow * ldA, smem + s * 1024);
      gll16(Bk + (size_t)(s * 8 + srow) * ldB, smem + 16384 + s * 1024);
    }
    __syncthreads();                            // staged data visible
    #pragma unroll
    for (int kq = 0; kq < 2; ++kq) {
      int sw = ((kq * 4 + q) ^ (i & 7)) * 16;   // swizzled read offset (bytes)
      bf8 af[4], bq[4];
      #pragma unroll
      for (int mt = 0; mt < 4; ++mt)
        af[mt] = *(const bf8*)(smem + (wm * 64 + mt * 16 + i) * 128 + sw);
      #pragma unroll
      for (int nt = 0; nt < 4; ++nt)
        bq[nt] = *(const bf8*)(smem + 16384 + (wn * 64 + nt * 16 + i) * 128 + sw);
      #pragma unroll
      for (int mt = 0; mt < 4; ++mt)
        #pragma unroll
        for (int nt = 0; nt < 4; ++nt)
          acc[mt][nt] = MFMA16(af[mt], bq[nt], acc[mt][nt]);
    }
  }
}

// ---------------- P0: transpose + convert x, fused weight casts ----------------
__global__ __launch_bounds__(256) void p0_fused(const float* __restrict__ x,
                                                short* __restrict__ xT,
                                                const float* __restrict__ Wk,
                                                const float* __restrict__ Wv,
                                                const float* __restrict__ Wo,
                                                short* __restrict__ Wkv_bf,
                                                short* __restrict__ Wo_bf) {
  __shared__ float lds[64][65];
  int id = blockIdx.x;
  int t = threadIdx.x;
  if (id >= 4096) {                              // weight-cast blocks
    int g = (id - 4096) * 256 + t;
    if (g < 262144) {
      int o = g >> 9, c = g & 511;
      float v = (o < 256) ? Wk[o * 512 + c] : Wv[(o - 256) * 512 + c];
      Wkv_bf[g] = f2bf(v);
    } else {
      int i2 = g - 262144;
      Wo_bf[i2] = f2bf(Wo[i2]);
    }
    return;
  }
  int cb = id & 7, sb = (id >> 3) & 15, b = id >> 7;
  int c0 = cb * 64, sp0 = sb * 64;
  const float4* x4 = reinterpret_cast<const float4*>(x);
  #pragma unroll
  for (int j = 0; j < 4; ++j) {
    int lin = t + 256 * j;
    int cl = lin >> 4, s4 = lin & 15;
    float4 v = x4[(((size_t)b * 512 + c0 + cl) * 1024 + sp0 + s4 * 4) >> 2];
    lds[cl][s4 * 4 + 0] = v.x; lds[cl][s4 * 4 + 1] = v.y;
    lds[cl][s4 * 4 + 2] = v.z; lds[cl][s4 * 4 + 3] = v.w;
  }
  __syncthreads();
  int spl = t >> 2, cs = (t & 3) * 16;
  bf8 o0, o1;
  #pragma unroll
  for (int j = 0; j < 8; ++j) o0[j] = f2bf(lds[cs + j][spl]);
  #pragma unroll
  for (int j = 0; j < 8; ++j) o1[j] = f2bf(lds[cs + 8 + j][spl]);
  size_t base = ((size_t)b * 1024 + sp0 + spl) * 512 + c0 + cs;
  *reinterpret_cast<bf8*>(xT + base) = o0;
  *reinterpret_cast<bf8*>(xT + base + 8) = o1;
}

// ---------------- K1: fused k/v projection GEMM (XCD-swizzled) ----------------
// slot<64: k-half, bm = xcd*32 + slot>>1, bn = slot&1 (A-tile pair-shared).
// slot>=64: v-half, b = xcd*4 + u>>4, s0 = ((u&15)>>1)*32, bn = 2+(u&1);
//   A rows permuted: mg = b*1024 + hi*256 + s0 + r32 -> vT writes coalesce.
// Both halves of one XCD touch the same 4MB xT window (L2-resident).
__global__ __launch_bounds__(256, 2) void k1_kv(const short* __restrict__ xT,
                                                const short* __restrict__ Wkv,
                                                const float* __restrict__ bk,
                                                const float* __restrict__ bv,
                                                short* __restrict__ kT,
                                                short* __restrict__ vT,
                                                float* __restrict__ s_part) {
  __shared__ __attribute__((aligned(16))) char smem[36864];
  f32x4 acc[4][4];
  int id = blockIdx.x;
  int xcd = id & 7, slot = id >> 3;              // 128 slots per XCD
  int tid = threadIdx.x;
  int w = tid >> 6, l = tid & 63, q = l >> 4, i = l & 15;
  int wm = w & 1, wn = w >> 1;

  if (slot < 64) {                               // ---- k half ----
    int bm = xcd * 32 + (slot >> 1);
    int bn = slot & 1;
    gemm_core<false>(xT + (size_t)bm * 128 * 512, Wkv + (size_t)bn * 128 * 512,
                     512, 512, 8, smem, acc);
    int mbase = bm * 128 + wm * 64;
    int nbase = bn * 128 + wn * 64;
    __syncthreads();                             // gemm tile reads done
    // per-wave LDS quadrant: 64 rows x 68 shorts (padded), 8704 B each
    short* st = (short*)smem + w * 4352;
    float rp[4][4];
    #pragma unroll
    for (int mt = 0; mt < 4; ++mt)
      #pragma unroll
      for (int r = 0; r < 4; ++r) rp[mt][r] = 0.f;
    #pragma unroll
    for (int mt = 0; mt < 4; ++mt)
      #pragma unroll
      for (int nt = 0; nt < 4; ++nt) {
        float bias = bk[nbase + nt * 16 + i];
        #pragma unroll
        for (int r = 0; r < 4; ++r) {
          float val = acc[mt][nt][r] + bias;
          st[(mt * 16 + q * 4 + r) * 68 + nt * 16 + i] = f2bf(val);
          rp[mt][r] += val;
        }
      }
    lgkm0();                                     // quadrant self-contained
    #pragma unroll
    for (int j = 0; j < 8; ++j) {                // coalesced 16B stores
      int row = j * 8 + (l >> 3), cc = l & 7;
      bf8 vv = *(const bf8*)(st + row * 68 + cc * 8);
      *(bf8*)(kT + (size_t)(mbase + row) * 256 + nbase + cc * 8) = vv;
    }
    #pragma unroll
    for (int mask = 1; mask <= 8; mask <<= 1)
      #pragma unroll
      for (int mt = 0; mt < 4; ++mt)
        #pragma unroll
        for (int r = 0; r < 4; ++r) rp[mt][r] += __shfl_xor(rp[mt][r], mask, 64);
    if (i == 0) {
      int pg = bn * 2 + wn;
      #pragma unroll
      for (int mt = 0; mt < 4; ++mt)
        #pragma unroll
        for (int r = 0; r < 4; ++r)
          s_part[pg * 32768 + mbase + mt * 16 + q * 4 + r] = rp[mt][r];
    }
  } else {                                       // ---- v half (permuted A) ----
    int u = slot - 64;
    int b = xcd * 4 + (u >> 4);
    int rem = u & 15;
    int s0 = (rem >> 1) * 32;
    int bn = 2 + (rem & 1);
    gemm_core<true>(xT + ((size_t)b * 1024 + s0) * 512,
                    Wkv + (size_t)bn * 128 * 512, 512, 512, 8, smem, acc);
    __syncthreads();                             // gemm tile reads done
    // block-shared restage tile: 32 rows (c_v) x 520 shorts (512 m + pad)
    short* st = (short*)smem;
    #pragma unroll
    for (int mt = 0; mt < 4; ++mt) {
      int hi2 = wm * 2 + (mt >> 1);              // hi = row_g>>5
      int r16 = (mt & 1) * 16;
      #pragma unroll
      for (int nt = 0; nt < 4; ++nt) {
        int o2 = (bn - 2) * 128 + wn * 64 + nt * 16 + i;
        float bias = bv[o2];
        int col = 4 * (wn * 64 + nt * 16 + i) + hi2;   // local m in [0,512)
        #pragma unroll
        for (int r = 0; r < 4; ++r)
          st[(r16 + q * 4 + r) * 520 + col] = f2bf(acc[mt][nt][r] + bias);
      }
    }
    __syncthreads();                             // tile is cross-wave
    // coalesced 16B stores: vT[(b*256+s0+row)*1024 + (bn-2)*512 + cc*8]
    short* vrow = vT + ((size_t)(b * 256 + s0)) * 1024 + (size_t)(bn - 2) * 512;
    #pragma unroll
    for (int ii = 0; ii < 8; ++ii) {
      int kp = tid + 256 * ii;
      int row = kp >> 6, cc = kp & 63;
      bf8 vv = *(const bf8*)(st + row * 520 + cc * 8);
      *(bf8*)(vrow + (size_t)row * 1024 + cc * 8) = vv;
    }
  }
}

// ---------------- K2 v2+fold: fused gram -> softmax -> PV -> OB ----------------
// (unchanged from R6 -- control at ~54us)
__global__ __launch_bounds__(256, 2) void k2_fused(const short* __restrict__ kT,
                                                   const short* __restrict__ vT,
                                                   const float* __restrict__ s_part,
                                                   short* __restrict__ OB) {
  __shared__ __attribute__((aligned(16))) char smem[81920];
  char* Apan = smem;            // 32 KB: 4 k-panels x (64 rows x 128 B)
  char* Ppan = smem + 32768;    // 16 KB: 2 panels x (64 rows x 128 B)
  char* Bst  = smem + 49152;    // 32 KB: 2 bufs x 4 waves x 4 KB

  const int id = blockIdx.x;
  const int xcd = id & 7, slot = id >> 3;
  const int b  = xcd * 4 + (slot >> 4);   // 4 batches per XCD (L2-resident)
  const int bm = slot & 15;

  const int tid = threadIdx.x;
  const int w = tid >> 6, l = tid & 63;
  const int q = l >> 4, i = l & 15;
  const int srow = l >> 3;
  const int gcol = ((l & 7) ^ srow) * 8;

  const short* kTb = kT + (size_t)b * 1024 * 256;
  const short* vTb = vT + (size_t)b * 256 * 1024;

  char* slabA = Bst + w * 4096;            // even rounds
  char* slabB = Bst + 16384 + w * 4096;    // odd rounds

  const float sc1 = 1.0f / 16384.0f;             // (1/M)/16
  const float sc2 = 1.0f / 16777216.0f;          // (1/M^2)/16

  // ---- issue resident-A staging FIRST (latency hidden under fold) ----
  {
    const short* Am = kTb + (size_t)bm * 64 * 256;
    #pragma unroll
    for (int ks = 0; ks < 4; ++ks)
      #pragma unroll
      for (int j2 = 0; j2 < 2; ++j2) {
        int s2 = w * 2 + j2;
        gll16(Am + (size_t)(s2 * 8 + srow) * 256 + ks * 64 + gcol,
              Apan + ks * 8192 + s2 * 1024);
      }
  }

  // ---- row-sum combine (ex-K1b), register sums ----
  const int mglob = b * 1024;
  float sm2[4][4];
  #pragma unroll
  for (int mt = 0; mt < 4; ++mt)
    #pragma unroll
    for (int r = 0; r < 4; ++r) {
      int m = mglob + bm * 64 + mt * 16 + q * 4 + r;
      sm2[mt][r] = (s_part[m] + s_part[32768 + m] + s_part[65536 + m] +
                    s_part[98304 + m]) * sc2;
    }
  float sn[8][2];
  #pragma unroll
  for (int c = 0; c < 8; ++c)
    #pragma unroll
    for (int nt = 0; nt < 2; ++nt) {
      int m = mglob + c * 128 + w * 32 + nt * 16 + i;
      sn[c][nt] = s_part[m] + s_part[32768 + m] + s_part[65536 + m] +
                  s_part[98304 + m];
    }

  // staging helpers: each wave stages exactly the rows its MFMAs read
  auto stageS = [&](int c, int ks, char* sl) {
    const short* Bn = kTb + (size_t)c * 128 * 256 + ks * 64 + gcol;
    #pragma unroll
    for (int j = 0; j < 4; ++j)
      gll16(Bn + (size_t)(w * 32 + j * 8 + srow) * 256, sl + j * 1024);
  };
  auto stageV = [&](int c, int ks2, int h, char* sl) {
    const short* Vn = vTb + c * 128 + ks2 * 64 + gcol;
    #pragma unroll
    for (int j = 0; j < 4; ++j)
      gll16(Vn + (size_t)(w * 64 + h * 32 + j * 8 + srow) * 1024, sl + j * 1024);
  };

  stageS(0, 0, slabA);                     // round 0
  stageS(0, 1, slabB);                     // round 1
  waitv<8>();                              // A landed; rounds 0/1 in flight
  barrier_relaxed();                       // A visible to all waves

  f32x4 zz = {0.f, 0.f, 0.f, 0.f};
  f32x4 acc_o[4][4];
  float rowsum[4][4];
  #pragma unroll
  for (int mt = 0; mt < 4; ++mt)
    #pragma unroll
    for (int ct = 0; ct < 4; ++ct) acc_o[mt][ct] = zz;
  #pragma unroll
  for (int mt = 0; mt < 4; ++mt)
    #pragma unroll
    for (int r = 0; r < 4; ++r) rowsum[mt][r] = 0.f;

  #pragma unroll
  for (int c = 0; c < 8; ++c) {
    f32x4 acc_s[4][2];
    #pragma unroll
    for (int mt = 0; mt < 4; ++mt)
      #pragma unroll
      for (int nt = 0; nt < 2; ++nt) acc_s[mt][nt] = zz;

    // ---- S rounds ks=0..3 (K=256): wait own vmcnt, compute, refill slab ----
    #pragma unroll
    for (int ks = 0; ks < 4; ++ks) {
      char* sl = (ks & 1) ? slabB : slabA;
      waitv<4>();                          // this round done; next in flight
      #pragma unroll
      for (int kq = 0; kq < 2; ++kq) {
        int sw = ((kq * 4 + q) ^ (i & 7)) * 16;
        bf8 af[4], bq2[2];
        #pragma unroll
        for (int mt = 0; mt < 4; ++mt)
          af[mt] = *(const bf8*)(Apan + ks * 8192 + (mt * 16 + i) * 128 + sw);
        #pragma unroll
        for (int nt = 0; nt < 2; ++nt)
          bq2[nt] = *(const bf8*)(sl + (nt * 16 + i) * 128 + sw);
        __builtin_amdgcn_s_setprio(1);
        #pragma unroll
        for (int mt = 0; mt < 4; ++mt)
          #pragma unroll
          for (int nt = 0; nt < 2; ++nt)
            acc_s[mt][nt] = MFMA16(af[mt], bq2[nt], acc_s[mt][nt]);
        __builtin_amdgcn_s_setprio(0);
      }
      lgkm0();                             // slab reads retired before refill
      if (ks < 2) stageS(c, ks + 2, sl);   // rounds 2,3: S ks+2
      else        stageV(c, 0, ks - 2, sl);// rounds 4,5: PV ks2=0, halves 0,1
    }

    // ---- exp -> P panels (PV rounds 4,5 in flight under this VALU work) ----
    barrier_relaxed();                     // prev chunk's P readers all done
    #pragma unroll
    for (int nt = 0; nt < 2; ++nt) {
      float snv = sn[c][nt];
      int nl = w * 32 + nt * 16 + i;
      char* pbase = Ppan + (nl >> 6) * 8192 + (nl & 7) * 2;
      int gchunk = (nl >> 3) & 7;
      #pragma unroll
      for (int mt = 0; mt < 4; ++mt)
        #pragma unroll
        for (int r = 0; r < 4; ++r) {
          int ml = mt * 16 + q * 4 + r;
          float p = __expf(acc_s[mt][nt][r] * sc1 - sm2[mt][r] * snv);
          rowsum[mt][r] += p;
          *(short*)(pbase + ml * 128 + ((gchunk ^ (ml & 7)) * 16)) = f2bf(p);
        }
    }
    lgkm0();                               // P writes complete
    barrier_relaxed();                     // P visible to all waves

    // ---- PV rounds (ks2,h) = (0,0),(0,1),(1,0),(1,1), K=128 ----
    #pragma unroll
    for (int pv = 0; pv < 4; ++pv) {
      char* sl = (pv & 1) ? slabB : slabA;
      const int ks2 = pv >> 1, h = pv & 1;
      if (c == 7 && pv == 3) waitv<0>(); else waitv<4>();
      #pragma unroll
      for (int kq = 0; kq < 2; ++kq) {
        int sw = ((kq * 4 + q) ^ (i & 7)) * 16;
        bf8 ap[4], bv2[2];
        #pragma unroll
        for (int mt = 0; mt < 4; ++mt)
          ap[mt] = *(const bf8*)(Ppan + ks2 * 8192 + (mt * 16 + i) * 128 + sw);
        #pragma unroll
        for (int u = 0; u < 2; ++u)
          bv2[u] = *(const bf8*)(sl + (u * 16 + i) * 128 + sw);
        __builtin_amdgcn_s_setprio(1);
        #pragma unroll
        for (int mt = 0; mt < 4; ++mt)
          #pragma unroll
          for (int u = 0; u < 2; ++u)
            acc_o[mt][h * 2 + u] = MFMA16(ap[mt], bv2[u], acc_o[mt][h * 2 + u]);
        __builtin_amdgcn_s_setprio(0);
      }
      lgkm0();
      if (pv < 2) stageV(c, 1, pv, sl);            // rounds 6,7: PV ks2=1
      else if (c < 7) stageS(c + 1, pv - 2, sl);   // next chunk S0,S1
    }
  }

  // ---- softmax rowsums: wave-reduce over i, block-reduce over waves ----
  #pragma unroll
  for (int mask = 1; mask <= 8; mask <<= 1)
    #pragma unroll
    for (int mt = 0; mt < 4; ++mt)
      #pragma unroll
      for (int r = 0; r < 4; ++r) rowsum[mt][r] += __shfl_xor(rowsum[mt][r], mask, 64);
  __syncthreads();                               // all PV P-reads done; reuse Ppan
  float* rs = (float*)Ppan;                      // [4 waves][64 m]
  if (i == 0) {
    #pragma unroll
    for (int mt = 0; mt < 4; ++mt)
      #pragma unroll
      for (int r = 0; r < 4; ++r)
        rs[w * 64 + mt * 16 + q * 4 + r] = rowsum[mt][r];
  }
  __syncthreads();
  float rinv[4][4];
  #pragma unroll
  for (int mt = 0; mt < 4; ++mt)
    #pragma unroll
    for (int r = 0; r < 4; ++r) {
      int m = mt * 16 + q * 4 + r;
      rinv[mt][r] = 1.0f / (rs[m] + rs[64 + m] + rs[128 + m] + rs[192 + m]);
    }
  // ---- normalize + OB write via per-wave LDS restage (self-contained slot) ----
  short* ob = (short*)(Bst + w * 8192);          // 256 rows x 16 shorts
  #pragma unroll
  for (int mt = 0; mt < 4; ++mt)
    #pragma unroll
    for (int ct = 0; ct < 4; ++ct)
      #pragma unroll
      for (int r = 0; r < 4; ++r)
        ob[(r * 64 + ct * 16 + i) * 16 + mt * 4 + q] =
            f2bf(acc_o[mt][ct][r] * rinv[mt][r]);
  short* obg = OB + (size_t)b * 1024 * 256;
  #pragma unroll
  for (int jj = 0; jj < 8; ++jj) {
    int lr = jj * 32 + (l >> 1), ch = l & 1;
    bf8 vv = *(const bf8*)(ob + lr * 16 + ch * 8);
    int rr = lr >> 6, cc = lr & 63;
    *(bf8*)(obg + ((size_t)(rr * 256 + w * 64 + cc)) * 256 + bm * 16 + ch * 8) = vv;
  }
}

// ---------------- K3: output projection + bias + residual (XCD-swizzled) ----------------
__global__ __launch_bounds__(256, 2) void k3_out(const short* __restrict__ Wo_bf,
                                                 const short* __restrict__ OB,
                                                 const float* __restrict__ bo,
                                                 const float* __restrict__ x,
                                                 float* __restrict__ out) {
  __shared__ __attribute__((aligned(16))) char smem[36864];
  f32x4 acc[4][4];
  // XCD-swizzle: each XCD owns 4 batches; bm fastest so 4 consecutive
  // blocks share the OB B-tile.
  int id = blockIdx.x;
  int xcd = id & 7, slot = id >> 3;              // 128 slots per XCD
  int b = xcd * 4 + (slot >> 5);
  int rem = slot & 31;
  int bn = rem >> 2, bm = rem & 3;
  gemm_core<false>(Wo_bf + (size_t)bm * 128 * 256,
                   OB + ((size_t)b * 1024 + bn * 128) * 256, 256, 256, 4,
                   smem, acc);
  int tid = threadIdx.x;
  int w = tid >> 6, l = tid & 63, q = l >> 4, i = l & 15;
  int wm = w & 1, wn = w >> 1;
  int oloc = bm * 128 + wm * 64, sploc = bn * 128 + wn * 64;
  __syncthreads();                               // gemm tile reads done
  // per-wave LDS quadrant: 32 rows x 66 f32 (padded), 8448 B each; 2 halves
  float* st = (float*)smem + w * 2112;
  #pragma unroll
  for (int half = 0; half < 2; ++half) {
    if (half) lgkm0();                           // half-0 reads retired
    #pragma unroll
    for (int mtl = 0; mtl < 2; ++mtl) {
      int mt = half * 2 + mtl;
      #pragma unroll
      for (int nt = 0; nt < 4; ++nt)
        #pragma unroll
        for (int r = 0; r < 4; ++r)
          st[(mtl * 16 + q * 4 + r) * 66 + nt * 16 + i] = acc[mt][nt][r];
    }
    lgkm0();                                     // quadrant self-contained
    #pragma unroll
    for (int j = 0; j < 8; ++j) {
      int row = j * 4 + (l >> 4), c4 = l & 15;
      f32x4 v = *(const f32x4*)(st + row * 66 + c4 * 4);
      int o = oloc + half * 32 + row;
      int sp = sploc + c4 * 4;
      size_t idx = ((size_t)b * 512 + o) * 1024 + sp;
      float4 xv = *(const float4*)(x + idx);
      float bias = bo[o];
      float4 ov;
      ov.x = v[0] + bias + xv.x;
      ov.y = v[1] + bias + xv.y;
      ov.z = v[2] + bias + xv.z;
      ov.w = v[3] + bias + xv.w;
      *(float4*)(out + idx) = ov;
    }
  }
}

extern "C" void kernel_launch(void* const* d_in, const int* in_sizes, int n_in,
                              void* d_out, int out_size, void* d_ws, size_t ws_size,
                              hipStream_t stream) {
  (void)in_sizes; (void)n_in; (void)out_size; (void)ws_size;
  const float* x  = (const float*)d_in[0];
  const float* Wk = (const float*)d_in[1];
  const float* bk = (const float*)d_in[2];
  const float* Wv = (const float*)d_in[3];
  const float* bv = (const float*)d_in[4];
  const float* Wo = (const float*)d_in[5];
  const float* bo = (const float*)d_in[6];
  float* out = (float*)d_out;
  char* ws = (char*)d_ws;

  // ws layout (~68.5 MB), time-aliased:
  //   [0,32M)   : xT (P0->K1, 32 MB) then OB (K2->K3, 16 MB)
  //   [32M,48M) : kT (K1->K2)
  //   [48M,64M) : vT (K1->K2)
  //   [64M,...) : weights + reduction buffers
  short* xT     = (short*)(ws);
  short* OB     = (short*)(ws);
  short* kTb    = (short*)(ws + 33554432);
  short* vTb    = (short*)(ws + 50331648);
  short* Wkv_bf = (short*)(ws + 67108864);
  short* Wo_bf  = (short*)(ws + 67633152);
  float* s_part = (float*)(ws + 67895296);

  p0_fused<<<5632, 256, 0, stream>>>(x, xT, Wk, Wv, Wo, Wkv_bf, Wo_bf);
  k1_kv<<<1024, 256, 0, stream>>>(xT, Wkv_bf, bk, bv, kTb, vTb, s_part);
  k2_fused<<<512, 256, 0, stream>>>(kTb, vTb, s_part, OB);
  k3_out<<<1024, 256, 0, stream>>>(Wo_bf, OB, bo, x, out);
}

// Round 8
// 218.350 us; speedup vs baseline: 1.5277x; 1.0154x over previous
//
#include <hip/hip_runtime.h>

// B=32, C=512, c2=256, M=1024. All GEMMs bf16 MFMA (fp32 accum), m97-style:
// 128x128 (or fused) tiles, BK=64, global_load_lds(16B) staging, XOR-swizzled
// chunks.
//
// P0 : x[b][c][sp] fp32 -> xT[b*1024+sp][c] bf16, FUSED with weight casts
// K1 : [32768x512]x[512x512], XCD-swizzled. k-half: kT + row-sum partials,
//      LDS-restaged 16B stores. v-half: A-rows permuted -> coalesced vT.
// K2 : FUSED flash-style attention, v5: ROLLED chunk loop (body ~5KB vs
//      ~37KB unrolled -- I-cache working set), sn row-sums computed
//      IN-GEMM via ones-vector MFMA (kills the c-indexed sn[8][2] array
//      that forced full unroll), counted vmcnt(4), 2 raw s_barriers/chunk,
//      setprio, XCD swizzle. LDS 80KB, 2 blocks/CU.
// K3 : out = Wo @ O2 + bo + x (R7-identical).

typedef short bf8 __attribute__((ext_vector_type(8)));
typedef float f32x4 __attribute__((ext_vector_type(4)));

#define MFMA16(a, b, c) __builtin_amdgcn_mfma_f32_16x16x32_bf16((a), (b), (c), 0, 0, 0)

__device__ __forceinline__ short f2bf(float x) {
  unsigned u = __float_as_uint(x);
  u += 0x7fffu + ((u >> 16) & 1u);   // RNE, finite inputs
  return (short)(u >> 16);
}

__device__ __forceinline__ void gll16(const short* g, void* l) {
  __builtin_amdgcn_global_load_lds(
      (const __attribute__((address_space(1))) unsigned int*)g,
      (__attribute__((address_space(3))) unsigned int*)l, 16, 0, 0);
}

__device__ __forceinline__ void lgkm0() {
  asm volatile("s_waitcnt lgkmcnt(0)" ::: "memory");
}
template <int N>
__device__ __forceinline__ void waitv() {
  static_assert(N == 0 || N == 4 || N == 8, "bad vmcnt");
  if constexpr (N == 0) asm volatile("s_waitcnt vmcnt(0)" ::: "memory");
  else if constexpr (N == 4) asm volatile("s_waitcnt vmcnt(4)" ::: "memory");
  else asm volatile("s_waitcnt vmcnt(8)" ::: "memory");
}
__device__ __forceinline__ void barrier_relaxed() {
  asm volatile("" ::: "memory");
  __builtin_amdgcn_s_barrier();
  asm volatile("" ::: "memory");
}

// ---- shared GEMM core (R1-proven): C[128][128] tile, single 32KB buffer.
// VPERM: A-tile rows permuted as row_g = w*256 + (j*8+srow) (v-half layout).
template <bool VPERM>
__device__ __forceinline__ void gemm_core(const short* __restrict__ A,
                                          const short* __restrict__ B,
                                          int ldA, int ldB, int ksteps,
                                          char* smem, f32x4 acc[4][4]) {
  const int tid = threadIdx.x;
  const int w = tid >> 6, l = tid & 63;
  const int q = l >> 4, i = l & 15;
  const int wm = w & 1, wn = w >> 1;
  const int srow = l >> 3;
  const int gcol = ((l & 7) ^ srow) * 8;        // swizzled 16B chunk (shorts)
  f32x4 zz = {0.f, 0.f, 0.f, 0.f};
  #pragma unroll
  for (int mt = 0; mt < 4; ++mt)
    #pragma unroll
    for (int nt = 0; nt < 4; ++nt) acc[mt][nt] = zz;

  for (int ks = 0; ks < ksteps; ++ks) {
    __syncthreads();                            // LDS free (prev reads done)
    const short* Ak = A + ks * 64 + gcol;
    const short* Bk = B + ks * 64 + gcol;
    #pragma unroll
    for (int j = 0; j < 4; ++j) {
      int s = w * 4 + j;
      size_t arow = VPERM ? (size_t)(w * 256 + j * 8 + srow)
                          : (size_t)(s * 8 + srow);
      gll16(Ak + arow * ldA, smem + s * 1024);
      gll16(Bk + (size_t)(s * 8 + srow) * ldB, smem + 16384 + s * 1024);
    }
    __syncthreads();                            // staged data visible
    #pragma unroll
    for (int kq = 0; kq < 2; ++kq) {
      int sw = ((kq * 4 + q) ^ (i & 7)) * 16;   // swizzled read offset (bytes)
      bf8 af[4], bq[4];
      #pragma unroll
      for (int mt = 0; mt < 4; ++mt)
        af[mt] = *(const bf8*)(smem + (wm * 64 + mt * 16 + i) * 128 + sw);
      #pragma unroll
      for (int nt = 0; nt < 4; ++nt)
        bq[nt] = *(const bf8*)(smem + 16384 + (wn * 64 + nt * 16 + i) * 128 + sw);
      #pragma unroll
      for (int mt = 0; mt < 4; ++mt)
        #pragma unroll
        for (int nt = 0; nt < 4; ++nt)
          acc[mt][nt] = MFMA16(af[mt], bq[nt], acc[mt][nt]);
    }
  }
}

// ---------------- P0: transpose + convert x, fused weight casts ----------------
__global__ __launch_bounds__(256) void p0_fused(const float* __restrict__ x,
                                                short* __restrict__ xT,
                                                const float* __restrict__ Wk,
                                                const float* __restrict__ Wv,
                                                const float* __restrict__ Wo,
                                                short* __restrict__ Wkv_bf,
                                                short* __restrict__ Wo_bf) {
  __shared__ float lds[64][65];
  int id = blockIdx.x;
  int t = threadIdx.x;
  if (id >= 4096) {                              // weight-cast blocks
    int g = (id - 4096) * 256 + t;
    if (g < 262144) {
      int o = g >> 9, c = g & 511;
      float v = (o < 256) ? Wk[o * 512 + c] : Wv[(o - 256) * 512 + c];
      Wkv_bf[g] = f2bf(v);
    } else {
      int i2 = g - 262144;
      Wo_bf[i2] = f2bf(Wo[i2]);
    }
    return;
  }
  int cb = id & 7, sb = (id >> 3) & 15, b = id >> 7;
  int c0 = cb * 64, sp0 = sb * 64;
  const float4* x4 = reinterpret_cast<const float4*>(x);
  #pragma unroll
  for (int j = 0; j < 4; ++j) {
    int lin = t + 256 * j;
    int cl = lin >> 4, s4 = lin & 15;
    float4 v = x4[(((size_t)b * 512 + c0 + cl) * 1024 + sp0 + s4 * 4) >> 2];
    lds[cl][s4 * 4 + 0] = v.x; lds[cl][s4 * 4 + 1] = v.y;
    lds[cl][s4 * 4 + 2] = v.z; lds[cl][s4 * 4 + 3] = v.w;
  }
  __syncthreads();
  int spl = t >> 2, cs = (t & 3) * 16;
  bf8 o0, o1;
  #pragma unroll
  for (int j = 0; j < 8; ++j) o0[j] = f2bf(lds[cs + j][spl]);
  #pragma unroll
  for (int j = 0; j < 8; ++j) o1[j] = f2bf(lds[cs + 8 + j][spl]);
  size_t base = ((size_t)b * 1024 + sp0 + spl) * 512 + c0 + cs;
  *reinterpret_cast<bf8*>(xT + base) = o0;
  *reinterpret_cast<bf8*>(xT + base + 8) = o1;
}

// ---------------- K1: fused k/v projection GEMM (XCD-swizzled) ----------------
__global__ __launch_bounds__(256, 2) void k1_kv(const short* __restrict__ xT,
                                                const short* __restrict__ Wkv,
                                                const float* __restrict__ bk,
                                                const float* __restrict__ bv,
                                                short* __restrict__ kT,
                                                short* __restrict__ vT,
                                                float* __restrict__ s_part) {
  __shared__ __attribute__((aligned(16))) char smem[36864];
  f32x4 acc[4][4];
  int id = blockIdx.x;
  int xcd = id & 7, slot = id >> 3;              // 128 slots per XCD
  int tid = threadIdx.x;
  int w = tid >> 6, l = tid & 63, q = l >> 4, i = l & 15;
  int wm = w & 1, wn = w >> 1;

  if (slot < 64) {                               // ---- k half ----
    int bm = xcd * 32 + (slot >> 1);
    int bn = slot & 1;
    gemm_core<false>(xT + (size_t)bm * 128 * 512, Wkv + (size_t)bn * 128 * 512,
                     512, 512, 8, smem, acc);
    int mbase = bm * 128 + wm * 64;
    int nbase = bn * 128 + wn * 64;
    __syncthreads();                             // gemm tile reads done
    // per-wave LDS quadrant: 64 rows x 68 shorts (padded), 8704 B each
    short* st = (short*)smem + w * 4352;
    float rp[4][4];
    #pragma unroll
    for (int mt = 0; mt < 4; ++mt)
      #pragma unroll
      for (int r = 0; r < 4; ++r) rp[mt][r] = 0.f;
    #pragma unroll
    for (int mt = 0; mt < 4; ++mt)
      #pragma unroll
      for (int nt = 0; nt < 4; ++nt) {
        float bias = bk[nbase + nt * 16 + i];
        #pragma unroll
        for (int r = 0; r < 4; ++r) {
          float val = acc[mt][nt][r] + bias;
          st[(mt * 16 + q * 4 + r) * 68 + nt * 16 + i] = f2bf(val);
          rp[mt][r] += val;
        }
      }
    lgkm0();                                     // quadrant self-contained
    #pragma unroll
    for (int j = 0; j < 8; ++j) {                // coalesced 16B stores
      int row = j * 8 + (l >> 3), cc = l & 7;
      bf8 vv = *(const bf8*)(st + row * 68 + cc * 8);
      *(bf8*)(kT + (size_t)(mbase + row) * 256 + nbase + cc * 8) = vv;
    }
    #pragma unroll
    for (int mask = 1; mask <= 8; mask <<= 1)
      #pragma unroll
      for (int mt = 0; mt < 4; ++mt)
        #pragma unroll
        for (int r = 0; r < 4; ++r) rp[mt][r] += __shfl_xor(rp[mt][r], mask, 64);
    if (i == 0) {
      int pg = bn * 2 + wn;
      #pragma unroll
      for (int mt = 0; mt < 4; ++mt)
        #pragma unroll
        for (int r = 0; r < 4; ++r)
          s_part[pg * 32768 + mbase + mt * 16 + q * 4 + r] = rp[mt][r];
    }
  } else {                                       // ---- v half (permuted A) ----
    int u = slot - 64;
    int b = xcd * 4 + (u >> 4);
    int rem = u & 15;
    int s0 = (rem >> 1) * 32;
    int bn = 2 + (rem & 1);
    gemm_core<true>(xT + ((size_t)b * 1024 + s0) * 512,
                    Wkv + (size_t)bn * 128 * 512, 512, 512, 8, smem, acc);
    __syncthreads();                             // gemm tile reads done
    // block-shared restage tile: 32 rows (c_v) x 520 shorts (512 m + pad)
    short* st = (short*)smem;
    #pragma unroll
    for (int mt = 0; mt < 4; ++mt) {
      int hi2 = wm * 2 + (mt >> 1);              // hi = row_g>>5
      int r16 = (mt & 1) * 16;
      #pragma unroll
      for (int nt = 0; nt < 4; ++nt) {
        int o2 = (bn - 2) * 128 + wn * 64 + nt * 16 + i;
        float bias = bv[o2];
        int col = 4 * (wn * 64 + nt * 16 + i) + hi2;   // local m in [0,512)
        #pragma unroll
        for (int r = 0; r < 4; ++r)
          st[(r16 + q * 4 + r) * 520 + col] = f2bf(acc[mt][nt][r] + bias);
      }
    }
    __syncthreads();                             // tile is cross-wave
    // coalesced 16B stores: vT[(b*256+s0+row)*1024 + (bn-2)*512 + cc*8]
    short* vrow = vT + ((size_t)(b * 256 + s0)) * 1024 + (size_t)(bn - 2) * 512;
    #pragma unroll
    for (int ii = 0; ii < 8; ++ii) {
      int kp = tid + 256 * ii;
      int row = kp >> 6, cc = kp & 63;
      bf8 vv = *(const bf8*)(st + row * 520 + cc * 8);
      *(bf8*)(vrow + (size_t)row * 1024 + cc * 8) = vv;
    }
  }
}

// ---------------- K2 v5: rolled-loop fused gram -> softmax -> PV -> OB ----------------
// LDS: Apan 32K resident | Ppan 16K | Bst 32K. Chunk loop ROLLED (8 iters,
// ~5KB body). sn[n] computed in-GEMM: ones-A MFMA against the staged kT
// fragments accumulates the channel sum alongside the gram. 2 blocks/CU.
__global__ __launch_bounds__(256, 2) void k2_fused(const short* __restrict__ kT,
                                                   const short* __restrict__ vT,
                                                   const float* __restrict__ s_part,
                                                   short* __restrict__ OB) {
  __shared__ __attribute__((aligned(16))) char smem[81920];
  char* Apan = smem;            // 32 KB: 4 k-panels x (64 rows x 128 B)
  char* Ppan = smem + 32768;    // 16 KB: 2 panels x (64 rows x 128 B)
  char* Bst  = smem + 49152;    // 32 KB: 2 bufs x 4 waves x 4 KB

  const int id = blockIdx.x;
  const int xcd = id & 7, slot = id >> 3;
  const int b  = xcd * 4 + (slot >> 4);   // 4 batches per XCD (L2-resident)
  const int bm = slot & 15;

  const int tid = threadIdx.x;
  const int w = tid >> 6, l = tid & 63;
  const int q = l >> 4, i = l & 15;
  const int srow = l >> 3;
  const int gcol = ((l & 7) ^ srow) * 8;

  const short* kTb = kT + (size_t)b * 1024 * 256;
  const short* vTb = vT + (size_t)b * 256 * 1024;

  char* slabA = Bst + w * 4096;            // even rounds
  char* slabB = Bst + 16384 + w * 4096;    // odd rounds

  const float sc1 = 1.0f / 16384.0f;             // (1/M)/16
  const float sc2 = 1.0f / 16777216.0f;          // (1/M^2)/16

  // ---- issue resident-A staging FIRST (latency hidden under fold) ----
  {
    const short* Am = kTb + (size_t)bm * 64 * 256;
    #pragma unroll
    for (int ks = 0; ks < 4; ++ks)
      #pragma unroll
      for (int j2 = 0; j2 < 2; ++j2) {
        int s2 = w * 2 + j2;
        gll16(Am + (size_t)(s2 * 8 + srow) * 256 + ks * 64 + gcol,
              Apan + ks * 8192 + s2 * 1024);
      }
  }

  // ---- m-row sums (ex-K1b fold), register; n-sums come from ones-MFMA ----
  const int mglob = b * 1024;
  float sm2[4][4];
  #pragma unroll
  for (int mt = 0; mt < 4; ++mt)
    #pragma unroll
    for (int r = 0; r < 4; ++r) {
      int m = mglob + bm * 64 + mt * 16 + q * 4 + r;
      sm2[mt][r] = (s_part[m] + s_part[32768 + m] + s_part[65536 + m] +
                    s_part[98304 + m]) * sc2;
    }

  // staging helpers: each wave stages exactly the rows its MFMAs read
  auto stageS = [&](int c, int ks, char* sl) {
    const short* Bn = kTb + (size_t)c * 128 * 256 + ks * 64 + gcol;
    #pragma unroll
    for (int j = 0; j < 4; ++j)
      gll16(Bn + (size_t)(w * 32 + j * 8 + srow) * 256, sl + j * 1024);
  };
  auto stageV = [&](int c, int ks2, int h, char* sl) {
    const short* Vn = vTb + c * 128 + ks2 * 64 + gcol;
    #pragma unroll
    for (int j = 0; j < 4; ++j)
      gll16(Vn + (size_t)(w * 64 + h * 32 + j * 8 + srow) * 1024, sl + j * 1024);
  };

  stageS(0, 0, slabA);                     // round 0
  stageS(0, 1, slabB);                     // round 1
  waitv<8>();                              // A landed; rounds 0/1 in flight
  barrier_relaxed();                       // A visible to all waves

  const short ONE = (short)0x3F80;         // bf16 1.0
  const bf8 af1 = {ONE, ONE, ONE, ONE, ONE, ONE, ONE, ONE};

  f32x4 zz = {0.f, 0.f, 0.f, 0.f};
  f32x4 acc_o[4][4];
  float rowsum[4][4];
  #pragma unroll
  for (int mt = 0; mt < 4; ++mt)
    #pragma unroll
    for (int ct = 0; ct < 4; ++ct) acc_o[mt][ct] = zz;
  #pragma unroll
  for (int mt = 0; mt < 4; ++mt)
    #pragma unroll
    for (int r = 0; r < 4; ++r) rowsum[mt][r] = 0.f;

  #pragma unroll 1                         // ROLLED: keep hot body in I-cache
  for (int c = 0; c < 8; ++c) {
    f32x4 acc_s[4][2];
    f32x4 acc1[2];                         // ones-MFMA: sn[n] channel sums
    #pragma unroll
    for (int mt = 0; mt < 4; ++mt)
      #pragma unroll
      for (int nt = 0; nt < 2; ++nt) acc_s[mt][nt] = zz;
    acc1[0] = zz; acc1[1] = zz;

    // ---- S rounds ks=0..3 (K=256): wait own vmcnt, compute, refill slab ----
    #pragma unroll
    for (int ks = 0; ks < 4; ++ks) {
      char* sl = (ks & 1) ? slabB : slabA;
      waitv<4>();                          // this round done; next in flight
      #pragma unroll
      for (int kq = 0; kq < 2; ++kq) {
        int sw = ((kq * 4 + q) ^ (i & 7)) * 16;
        bf8 af[4], bq2[2];
        #pragma unroll
        for (int mt = 0; mt < 4; ++mt)
          af[mt] = *(const bf8*)(Apan + ks * 8192 + (mt * 16 + i) * 128 + sw);
        #pragma unroll
        for (int nt = 0; nt < 2; ++nt)
          bq2[nt] = *(const bf8*)(sl + (nt * 16 + i) * 128 + sw);
        __builtin_amdgcn_s_setprio(1);
        #pragma unroll
        for (int mt = 0; mt < 4; ++mt)
          #pragma unroll
          for (int nt = 0; nt < 2; ++nt)
            acc_s[mt][nt] = MFMA16(af[mt], bq2[nt], acc_s[mt][nt]);
        acc1[0] = MFMA16(af1, bq2[0], acc1[0]);
        acc1[1] = MFMA16(af1, bq2[1], acc1[1]);
        __builtin_amdgcn_s_setprio(0);
      }
      lgkm0();                             // slab reads retired before refill
      if (ks < 2) stageS(c, ks + 2, sl);   // rounds 2,3: S ks+2
      else        stageV(c, 0, ks - 2, sl);// rounds 4,5: PV ks2=0, halves 0,1
    }

    // ---- exp -> P panels (PV rounds 4,5 in flight under this VALU work) ----
    barrier_relaxed();                     // prev chunk's P readers all done
    #pragma unroll
    for (int nt = 0; nt < 2; ++nt) {
      float snv = acc1[nt][0];             // sn[n], n = c*128 + w*32 + nt*16 + i
      int nl = w * 32 + nt * 16 + i;
      char* pbase = Ppan + (nl >> 6) * 8192 + (nl & 7) * 2;
      int gchunk = (nl >> 3) & 7;
      #pragma unroll
      for (int mt = 0; mt < 4; ++mt)
        #pragma unroll
        for (int r = 0; r < 4; ++r) {
          int ml = mt * 16 + q * 4 + r;
          float p = __expf(acc_s[mt][nt][r] * sc1 - sm2[mt][r] * snv);
          rowsum[mt][r] += p;
          *(short*)(pbase + ml * 128 + ((gchunk ^ (ml & 7)) * 16)) = f2bf(p);
        }
    }
    lgkm0();                               // P writes complete
    barrier_relaxed();                     // P visible to all waves

    // ---- PV rounds (ks2,h) = (0,0),(0,1),(1,0),(1,1), K=128 ----
    #pragma unroll
    for (int pv = 0; pv < 4; ++pv) {
      char* sl = (pv & 1) ? slabB : slabA;
      const int ks2 = pv >> 1, h = pv & 1;
      if (c == 7 && pv == 3) waitv<0>(); else waitv<4>();
      #pragma unroll
      for (int kq = 0; kq < 2; ++kq) {
        int sw = ((kq * 4 + q) ^ (i & 7)) * 16;
        bf8 ap[4], bv2[2];
        #pragma unroll
        for (int mt = 0; mt < 4; ++mt)
          ap[mt] = *(const bf8*)(Ppan + ks2 * 8192 + (mt * 16 + i) * 128 + sw);
        #pragma unroll
        for (int u = 0; u < 2; ++u)
          bv2[u] = *(const bf8*)(sl + (u * 16 + i) * 128 + sw);
        __builtin_amdgcn_s_setprio(1);
        #pragma unroll
        for (int mt = 0; mt < 4; ++mt)
          #pragma unroll
          for (int u = 0; u < 2; ++u)
            acc_o[mt][h * 2 + u] = MFMA16(ap[mt], bv2[u], acc_o[mt][h * 2 + u]);
        __builtin_amdgcn_s_setprio(0);
      }
      lgkm0();
      if (pv < 2) stageV(c, 1, pv, sl);            // rounds 6,7: PV ks2=1
      else if (c < 7) stageS(c + 1, pv - 2, sl);   // next chunk S0,S1
    }
  }

  // ---- softmax rowsums: wave-reduce over i, block-reduce over waves ----
  #pragma unroll
  for (int mask = 1; mask <= 8; mask <<= 1)
    #pragma unroll
    for (int mt = 0; mt < 4; ++mt)
      #pragma unroll
      for (int r = 0; r < 4; ++r) rowsum[mt][r] += __shfl_xor(rowsum[mt][r], mask, 64);
  __syncthreads();                               // all PV P-reads done; reuse Ppan
  float* rs = (float*)Ppan;                      // [4 waves][64 m]
  if (i == 0) {
    #pragma unroll
    for (int mt = 0; mt < 4; ++mt)
      #pragma unroll
      for (int r = 0; r < 4; ++r)
        rs[w * 64 + mt * 16 + q * 4 + r] = rowsum[mt][r];
  }
  __syncthreads();
  float rinv[4][4];
  #pragma unroll
  for (int mt = 0; mt < 4; ++mt)
    #pragma unroll
    for (int r = 0; r < 4; ++r) {
      int m = mt * 16 + q * 4 + r;
      rinv[mt][r] = 1.0f / (rs[m] + rs[64 + m] + rs[128 + m] + rs[192 + m]);
    }
  // ---- normalize + OB write via per-wave LDS restage (self-contained slot) ----
  short* ob = (short*)(Bst + w * 8192);          // 256 rows x 16 shorts
  #pragma unroll
  for (int mt = 0; mt < 4; ++mt)
    #pragma unroll
    for (int ct = 0; ct < 4; ++ct)
      #pragma unroll
      for (int r = 0; r < 4; ++r)
        ob[(r * 64 + ct * 16 + i) * 16 + mt * 4 + q] =
            f2bf(acc_o[mt][ct][r] * rinv[mt][r]);
  short* obg = OB + (size_t)b * 1024 * 256;
  #pragma unroll
  for (int jj = 0; jj < 8; ++jj) {
    int lr = jj * 32 + (l >> 1), ch = l & 1;
    bf8 vv = *(const bf8*)(ob + lr * 16 + ch * 8);
    int rr = lr >> 6, cc = lr & 63;
    *(bf8*)(obg + ((size_t)(rr * 256 + w * 64 + cc)) * 256 + bm * 16 + ch * 8) = vv;
  }
}

// ---------------- K3: output projection + bias + residual (XCD-swizzled) ----------------
__global__ __launch_bounds__(256, 2) void k3_out(const short* __restrict__ Wo_bf,
                                                 const short* __restrict__ OB,
                                                 const float* __restrict__ bo,
                                                 const float* __restrict__ x,
                                                 float* __restrict__ out) {
  __shared__ __attribute__((aligned(16))) char smem[36864];
  f32x4 acc[4][4];
  int id = blockIdx.x;
  int xcd = id & 7, slot = id >> 3;              // 128 slots per XCD
  int b = xcd * 4 + (slot >> 5);
  int rem = slot & 31;
  int bn = rem >> 2, bm = rem & 3;
  gemm_core<false>(Wo_bf + (size_t)bm * 128 * 256,
                   OB + ((size_t)b * 1024 + bn * 128) * 256, 256, 256, 4,
                   smem, acc);
  int tid = threadIdx.x;
  int w = tid >> 6, l = tid & 63, q = l >> 4, i = l & 15;
  int wm = w & 1, wn = w >> 1;
  int oloc = bm * 128 + wm * 64, sploc = bn * 128 + wn * 64;
  __syncthreads();                               // gemm tile reads done
  // per-wave LDS quadrant: 32 rows x 66 f32 (padded), 8448 B each; 2 halves
  float* st = (float*)smem + w * 2112;
  #pragma unroll
  for (int half = 0; half < 2; ++half) {
    if (half) lgkm0();                           // half-0 reads retired
    #pragma unroll
    for (int mtl = 0; mtl < 2; ++mtl) {
      int mt = half * 2 + mtl;
      #pragma unroll
      for (int nt = 0; nt < 4; ++nt)
        #pragma unroll
        for (int r = 0; r < 4; ++r)
          st[(mtl * 16 + q * 4 + r) * 66 + nt * 16 + i] = acc[mt][nt][r];
    }
    lgkm0();                                     // quadrant self-contained
    #pragma unroll
    for (int j = 0; j < 8; ++j) {
      int row = j * 4 + (l >> 4), c4 = l & 15;
      f32x4 v = *(const f32x4*)(st + row * 66 + c4 * 4);
      int o = oloc + half * 32 + row;
      int sp = sploc + c4 * 4;
      size_t idx = ((size_t)b * 512 + o) * 1024 + sp;
      float4 xv = *(const float4*)(x + idx);
      float bias = bo[o];
      float4 ov;
      ov.x = v[0] + bias + xv.x;
      ov.y = v[1] + bias + xv.y;
      ov.z = v[2] + bias + xv.z;
      ov.w = v[3] + bias + xv.w;
      *(float4*)(out + idx) = ov;
    }
  }
}

extern "C" void kernel_launch(void* const* d_in, const int* in_sizes, int n_in,
                              void* d_out, int out_size, void* d_ws, size_t ws_size,
                              hipStream_t stream) {
  (void)in_sizes; (void)n_in; (void)out_size; (void)ws_size;
  const float* x  = (const float*)d_in[0];
  const float* Wk = (const float*)d_in[1];
  const float* bk = (const float*)d_in[2];
  const float* Wv = (const float*)d_in[3];
  const float* bv = (const float*)d_in[4];
  const float* Wo = (const float*)d_in[5];
  const float* bo = (const float*)d_in[6];
  float* out = (float*)d_out;
  char* ws = (char*)d_ws;

  // ws layout (~68.5 MB), time-aliased:
  //   [0,32M)   : xT (P0->K1, 32 MB) then OB (K2->K3, 16 MB)
  //   [32M,48M) : kT (K1->K2)
  //   [48M,64M) : vT (K1->K2)
  //   [64M,...) : weights + reduction buffers
  short* xT     = (short*)(ws);
  short* OB     = (short*)(ws);
  short* kTb    = (short*)(ws + 33554432);
  short* vTb    = (short*)(ws + 50331648);
  short* Wkv_bf = (short*)(ws + 67108864);
  short* Wo_bf  = (short*)(ws + 67633152);
  float* s_part = (float*)(ws + 67895296);

  p0_fused<<<5632, 256, 0, stream>>>(x, xT, Wk, Wv, Wo, Wkv_bf, Wo_bf);
  k1_kv<<<1024, 256, 0, stream>>>(xT, Wkv_bf, bk, bv, kTb, vTb, s_part);
  k2_fused<<<512, 256, 0, stream>>>(kTb, vTb, s_part, OB);
  k3_out<<<1024, 256, 0, stream>>>(Wo_bf, OB, bo, x, out);
}